// Round 2
// baseline (1441.097 us; speedup 1.0000x reference)
//
#include <hip/hip_runtime.h>
#include <hip/hip_bf16.h>

// Round 2: edge MLPs on bf16 MFMA (16x16x32), 16 edges per wave-tile.
// D = A*B with A = W^T (channels x K), B = act^T (K x edges) so that the
// C-layout (col = lane&15 = edge) chains into the next layer's B-frag via a
// small XOR-swizzled per-wave LDS transpose. No __syncthreads in main loop.

using bf16x8 = __attribute__((ext_vector_type(8))) short;
using f32x4  = __attribute__((ext_vector_type(4))) float;

__device__ __forceinline__ uint16_t f2bfu(float f) {
  union { float f; uint32_t u; } v; v.f = f;
  uint32_t r = v.u + 0x7fffu + ((v.u >> 16) & 1u);
  return (uint16_t)(r >> 16);
}
__device__ __forceinline__ float bf2f(short s) {
  union { uint32_t u; float f; } v; v.u = ((uint32_t)(uint16_t)s) << 16;
  return v.f;
}
__device__ __forceinline__ uint32_t pk2(float a, float b) {
  return (uint32_t)f2bfu(a) | ((uint32_t)f2bfu(b) << 16);
}
__device__ __forceinline__ f32x4 mfma16(bf16x8 a, bf16x8 b, f32x4 c) {
  return __builtin_amdgcn_mfma_f32_16x16x32_bf16(a, b, c, 0, 0, 0);
}

#define WAVES_PER_BLOCK 4

// ---------------- edge kernel (MFMA) ----------------
__global__ __launch_bounds__(256) void edge_mfma_kernel(
    const float* __restrict__ pos,
    const float* __restrict__ v, const float* __restrict__ a_src, const float* __restrict__ a_dst,
    const float* __restrict__ pW1, const float* __restrict__ pb1,
    const float* __restrict__ pW2, const float* __restrict__ pb2,
    const float* __restrict__ aW1, const float* __restrict__ ab1,
    const float* __restrict__ aW2, const float* __restrict__ ab2,
    const int* __restrict__ eidx,
    float* __restrict__ num, float* __restrict__ den, int E) {
  // weight A-frags: [m(3)][half(2)][t(4)] x 64 lanes x 4 dwords (8 bf16)
  __shared__ uint32_t sWfrag[24][64][4];   // 24 KB
  __shared__ float    sSmall[448];         // pW1(192) pb1(64) pb2(64) ab1(64) ab2(64)
  __shared__ uint8_t  sTr[WAVES_PER_BLOCK][2048];  // per-wave 16 x 128B transpose buf

  const int tid = threadIdx.x;
  // ---- stage small params ----
  for (int i = tid; i < 448; i += 256) {
    float val;
    if      (i < 192) val = pW1[i];
    else if (i < 256) val = pb1[i - 192];
    else if (i < 320) val = pb2[i - 256];
    else if (i < 384) val = ab1[i - 320];
    else              val = ab2[i - 384];
    sSmall[i] = val;
  }
  // ---- build weight fragments (A-operand layout: A[c_local=lo][k=(hi)*8+i]) ----
  for (int idx = tid; idx < 24 * 64; idx += 256) {
    const int f = idx >> 6, lane = idx & 63;
    const int m = f >> 3, half = (f >> 2) & 1, t = f & 3;
    const float* W = (m == 0) ? pW2 : (m == 1) ? aW1 : aW2;
    const int lo = lane & 15, hi = lane >> 4;
    const int c = t * 16 + lo;
    uint32_t dw[4];
#pragma unroll
    for (int p = 0; p < 4; ++p) {
      const int k = 32 * half + hi * 8 + 2 * p;
      dw[p] = (uint32_t)f2bfu(W[k * 64 + c]) | ((uint32_t)f2bfu(W[(k + 1) * 64 + c]) << 16);
    }
    uint4 q; q.x = dw[0]; q.y = dw[1]; q.z = dw[2]; q.w = dw[3];
    *(uint4*)&sWfrag[f][lane][0] = q;
  }
  __syncthreads();

  const int w  = tid >> 6, l = tid & 63;
  const int lo = l & 15,  hi = l >> 4;
  uint8_t* trbase = &sTr[w][0];
  const uint32_t swz = (uint32_t)((lo & 7) << 4);

#define WF(m, half, t) (*(const bf16x8*)&sWfrag[(m) * 8 + (half) * 4 + (t)][l][0])

  const int ntiles = (E + 15) >> 4;
  for (int tile = blockIdx.x * WAVES_PER_BLOCK + w; tile < ntiles;
       tile += gridDim.x * WAVES_PER_BLOCK) {
    const int e = tile * 16 + lo;
    const bool valid = e < E;
    const int ec = valid ? e : (E - 1);
    const int src = eidx[ec];
    const int dst = eidx[E + ec];
    const float d0 = pos[dst * 3 + 0] - pos[src * 3 + 0];
    const float d1 = pos[dst * 3 + 1] - pos[src * 3 + 1];
    const float d2 = pos[dst * 3 + 2] - pos[src * 3 + 2];

    // ---- pos layer 1 (3->64), directly in B-frag layout: edge=lo, k=32h+8hi+i
    bf16x8 hf[2];
#pragma unroll
    for (int half = 0; half < 2; ++half) {
#pragma unroll
      for (int i = 0; i < 8; ++i) {
        const int k = 32 * half + hi * 8 + i;
        float h = sSmall[192 + k] + d0 * sSmall[k] + d1 * sSmall[64 + k] + d2 * sSmall[128 + k];
        hf[half][i] = (short)f2bfu(fmaxf(h, 0.f));
      }
    }
    // ---- pos layer 2 (64->64) via MFMA; delta in C-layout regs
    f32x4 dl[4];
#pragma unroll
    for (int t = 0; t < 4; ++t) {
      f32x4 acc = *(const f32x4*)&sSmall[256 + t * 16 + hi * 4];
      acc = mfma16(WF(0, 0, t), hf[0], acc);
      acc = mfma16(WF(0, 1, t), hf[1], acc);
#pragma unroll
      for (int r = 0; r < 4; ++r) dl[t][r] = fmaxf(acc[r], 0.f);
    }
    // ---- transpose delta C-layout -> B-layout via wave-private LDS (bf16, XOR swizzle)
    asm volatile("s_waitcnt lgkmcnt(0)" ::: "memory");  // prior reads of trbuf done
#pragma unroll
    for (int t = 0; t < 4; ++t) {
      uint2 p; p.x = pk2(dl[t][0], dl[t][1]); p.y = pk2(dl[t][2], dl[t][3]);
      *(uint2*)(trbase + lo * 128 + (((uint32_t)(t * 32 + hi * 8)) ^ swz)) = p;
    }
    asm volatile("s_waitcnt lgkmcnt(0)" ::: "memory");
    // ---- attn input: a_dst[dst] - a_src[src] + delta, in B-frag layout
    bf16x8 tf[2];
#pragma unroll
    for (int half = 0; half < 2; ++half) {
      bf16x8 dfr = *(const bf16x8*)(trbase + lo * 128 + (((uint32_t)(half * 64 + hi * 16)) ^ swz));
      const int base = 32 * half + hi * 8;
      const f32x4 A0 = *(const f32x4*)&a_dst[(size_t)dst * 64 + base];
      const f32x4 A1 = *(const f32x4*)&a_dst[(size_t)dst * 64 + base + 4];
      const f32x4 S0 = *(const f32x4*)&a_src[(size_t)src * 64 + base];
      const f32x4 S1 = *(const f32x4*)&a_src[(size_t)src * 64 + base + 4];
#pragma unroll
      for (int i = 0; i < 8; ++i) {
        const float av = ((i < 4) ? A0[i] : A1[i - 4]) - ((i < 4) ? S0[i] : S1[i - 4]) + bf2f(dfr[i]);
        tf[half][i] = (short)f2bfu(av);
      }
    }
    // ---- attn layer 1
    f32x4 ga[4];
#pragma unroll
    for (int t = 0; t < 4; ++t) {
      f32x4 acc = *(const f32x4*)&sSmall[320 + t * 16 + hi * 4];
      acc = mfma16(WF(1, 0, t), tf[0], acc);
      acc = mfma16(WF(1, 1, t), tf[1], acc);
#pragma unroll
      for (int r = 0; r < 4; ++r) ga[t][r] = fmaxf(acc[r], 0.f);
    }
    // ---- transpose gg (already relu'd; read back directly as bf16 frag)
    asm volatile("s_waitcnt lgkmcnt(0)" ::: "memory");
#pragma unroll
    for (int t = 0; t < 4; ++t) {
      uint2 p; p.x = pk2(ga[t][0], ga[t][1]); p.y = pk2(ga[t][2], ga[t][3]);
      *(uint2*)(trbase + lo * 128 + (((uint32_t)(t * 32 + hi * 8)) ^ swz)) = p;
    }
    asm volatile("s_waitcnt lgkmcnt(0)" ::: "memory");
    bf16x8 gf0 = *(const bf16x8*)(trbase + lo * 128 + (((uint32_t)(0 * 64 + hi * 16)) ^ swz));
    bf16x8 gf1 = *(const bf16x8*)(trbase + lo * 128 + (((uint32_t)(1 * 64 + hi * 16)) ^ swz));
    // ---- attn layer 2 -> alpha -> ex -> atomics
#pragma unroll
    for (int t = 0; t < 4; ++t) {
      f32x4 acc = *(const f32x4*)&sSmall[384 + t * 16 + hi * 4];
      acc = mfma16(WF(2, 0, t), gf0, acc);
      acc = mfma16(WF(2, 1, t), gf1, acc);
      const f32x4 vv = *(const f32x4*)&v[(size_t)src * 64 + t * 16 + hi * 4];
#pragma unroll
      for (int r = 0; r < 4; ++r) {
        const float alpha = fmaxf(acc[r], 0.f);
        const float ex = __expf(alpha);
        if (valid) {
          const int c = t * 16 + hi * 4 + r;
          atomicAdd(&den[(size_t)dst * 64 + c], ex);
          atomicAdd(&num[(size_t)dst * 64 + c], ex * (vv[r] + dl[t][r]));
        }
      }
    }
  }
#undef WF
}

// ---------------- node kernels (unchanged from round 1) ----------------
__global__ __launch_bounds__(256) void node_in_kernel(
    const float* __restrict__ x, const float* __restrict__ W_in, const float* __restrict__ b_in,
    const float* __restrict__ W_lin, const float* __restrict__ W_src, const float* __restrict__ W_dst,
    float* __restrict__ v, float* __restrict__ a_src, float* __restrict__ a_dst, int N) {
  __shared__ float sW[3 * 4096];
  __shared__ float sb[64];
  __shared__ float xbuf[WAVES_PER_BLOCK][64];
  __shared__ float x1buf[WAVES_PER_BLOCK][64];
  for (int i = threadIdx.x; i < 4096; i += 256) {
    sW[i] = W_in[i]; sW[4096 + i] = W_lin[i]; sW[8192 + i] = W_src[i];
  }
  if (threadIdx.x < 64) sb[threadIdx.x] = b_in[threadIdx.x];
  __syncthreads();
  const int w = threadIdx.x >> 6, c = threadIdx.x & 63;
  const int npi = gridDim.x * WAVES_PER_BLOCK;
  const int iters = (N + npi - 1) / npi;
  for (int it = 0; it < iters; ++it) {
    const int n = it * npi + blockIdx.x * WAVES_PER_BLOCK + w;
    const bool act = n < N;
    xbuf[w][c] = act ? x[n * 64 + c] : 0.f;
    __syncthreads();
    float acc = sb[c];
#pragma unroll
    for (int k = 0; k < 64; ++k) acc += xbuf[w][k] * sW[k * 64 + c];
    x1buf[w][c] = fmaxf(acc, 0.f);
    __syncthreads();
    float av = 0.f, as = 0.f, ad = 0.f;
#pragma unroll
    for (int k = 0; k < 64; ++k) {
      const float xv = x1buf[w][k];
      av += xv * sW[4096 + k * 64 + c];
      as += xv * sW[8192 + k * 64 + c];
      ad += xv * W_dst[k * 64 + c];
    }
    if (act) { v[n * 64 + c] = av; a_src[n * 64 + c] = as; a_dst[n * 64 + c] = ad; }
    __syncthreads();
  }
}

__global__ __launch_bounds__(256) void node_out_kernel(
    const float* __restrict__ num, const float* __restrict__ den,
    const float* __restrict__ W_out, const float* __restrict__ b_out,
    float* __restrict__ out, int N) {
  __shared__ float sW[4096];
  __shared__ float sb[64];
  __shared__ float sbuf[WAVES_PER_BLOCK][64];
  for (int i = threadIdx.x; i < 4096; i += 256) sW[i] = W_out[i];
  if (threadIdx.x < 64) sb[threadIdx.x] = b_out[threadIdx.x];
  __syncthreads();
  const int w = threadIdx.x >> 6, c = threadIdx.x & 63;
  const int npi = gridDim.x * WAVES_PER_BLOCK;
  const int iters = (N + npi - 1) / npi;
  for (int it = 0; it < iters; ++it) {
    const int n = it * npi + blockIdx.x * WAVES_PER_BLOCK + w;
    const bool act = n < N;
    float s = 0.f;
    if (act) {
      const float d = den[n * 64 + c];
      s = num[n * 64 + c] / (d + 1e-16f);
    }
    sbuf[w][c] = s;
    __syncthreads();
    float acc = sb[c];
#pragma unroll
    for (int k = 0; k < 64; ++k) acc += sbuf[w][k] * sW[k * 64 + c];
    if (act) out[n * 64 + c] = fmaxf(acc, 0.f);
    __syncthreads();
  }
}

extern "C" void kernel_launch(void* const* d_in, const int* in_sizes, int n_in,
                              void* d_out, int out_size, void* d_ws, size_t ws_size,
                              hipStream_t stream) {
  const float* x     = (const float*)d_in[0];
  const float* pos   = (const float*)d_in[1];
  const float* W_in  = (const float*)d_in[2];
  const float* b_in  = (const float*)d_in[3];
  const float* W_lin = (const float*)d_in[4];
  const float* W_src = (const float*)d_in[5];
  const float* W_dst = (const float*)d_in[6];
  const float* pW1   = (const float*)d_in[7];
  const float* pb1   = (const float*)d_in[8];
  const float* pW2   = (const float*)d_in[9];
  const float* pb2   = (const float*)d_in[10];
  const float* aW1   = (const float*)d_in[11];
  const float* ab1   = (const float*)d_in[12];
  const float* aW2   = (const float*)d_in[13];
  const float* ab2   = (const float*)d_in[14];
  const float* W_out = (const float*)d_in[15];
  const float* b_out = (const float*)d_in[16];
  const int*   eidx  = (const int*)d_in[17];

  const int N = in_sizes[0] / 64;
  const int E = in_sizes[17] / 2;

  float* ws    = (float*)d_ws;
  float* v     = ws;
  float* a_src = ws + (size_t)1 * N * 64;
  float* a_dst = ws + (size_t)2 * N * 64;
  float* num   = ws + (size_t)3 * N * 64;
  float* den   = ws + (size_t)4 * N * 64;

  hipMemsetAsync(num, 0, (size_t)2 * N * 64 * sizeof(float), stream);

  node_in_kernel<<<1024, 256, 0, stream>>>(x, W_in, b_in, W_lin, W_src, W_dst,
                                           v, a_src, a_dst, N);
  edge_mfma_kernel<<<1024, 256, 0, stream>>>(pos, v, a_src, a_dst,
                                             pW1, pb1, pW2, pb2, aW1, ab1, aW2, ab2,
                                             eidx, num, den, E);
  node_out_kernel<<<1024, 256, 0, stream>>>(num, den, W_out, b_out, (float*)d_out, N);
}

// Round 3
// 455.131 us; speedup vs baseline: 3.1663x; 3.1663x over previous
//
#include <hip/hip_runtime.h>
#include <hip/hip_bf16.h>

// Round 3: MFMA edge MLPs (as round 2) + COALESCED atomic epilogue.
// C-layout results are transposed through a wave-private LDS tile so each
// atomic instruction covers 64 contiguous channels of one dst row (256B).

using bf16x8 = __attribute__((ext_vector_type(8))) short;
using f32x4  = __attribute__((ext_vector_type(4))) float;

__device__ __forceinline__ uint16_t f2bfu(float f) {
  union { float f; uint32_t u; } v; v.f = f;
  uint32_t r = v.u + 0x7fffu + ((v.u >> 16) & 1u);
  return (uint16_t)(r >> 16);
}
__device__ __forceinline__ float bf2f(short s) {
  union { uint32_t u; float f; } v; v.u = ((uint32_t)(uint16_t)s) << 16;
  return v.f;
}
__device__ __forceinline__ uint32_t pk2(float a, float b) {
  return (uint32_t)f2bfu(a) | ((uint32_t)f2bfu(b) << 16);
}
__device__ __forceinline__ f32x4 mfma16(bf16x8 a, bf16x8 b, f32x4 c) {
  return __builtin_amdgcn_mfma_f32_16x16x32_bf16(a, b, c, 0, 0, 0);
}

#define WAVES_PER_BLOCK 4

__global__ __launch_bounds__(256) void edge_mfma_kernel(
    const float* __restrict__ pos,
    const float* __restrict__ v, const float* __restrict__ a_src, const float* __restrict__ a_dst,
    const float* __restrict__ pW1, const float* __restrict__ pb1,
    const float* __restrict__ pW2, const float* __restrict__ pb2,
    const float* __restrict__ aW1, const float* __restrict__ ab1,
    const float* __restrict__ aW2, const float* __restrict__ ab2,
    const int* __restrict__ eidx,
    float* __restrict__ num, float* __restrict__ den, int E) {
  __shared__ uint32_t sWfrag[24][64][4];                 // 24 KB weight A-frags
  __shared__ float    sSmall[448];                       // pW1/pb1/pb2/ab1/ab2
  __shared__ float    sXp[WAVES_PER_BLOCK][16 * 68];     // 4.25KB/wave transpose buf
  __shared__ int      sDst[WAVES_PER_BLOCK][16];

  const int tid = threadIdx.x;
  for (int i = tid; i < 448; i += 256) {
    float val;
    if      (i < 192) val = pW1[i];
    else if (i < 256) val = pb1[i - 192];
    else if (i < 320) val = pb2[i - 256];
    else if (i < 384) val = ab1[i - 320];
    else              val = ab2[i - 384];
    sSmall[i] = val;
  }
  for (int idx = tid; idx < 24 * 64; idx += 256) {
    const int f = idx >> 6, lane = idx & 63;
    const int m = f >> 3, half = (f >> 2) & 1, t = f & 3;
    const float* W = (m == 0) ? pW2 : (m == 1) ? aW1 : aW2;
    const int lo = lane & 15, hi = lane >> 4;
    const int c = t * 16 + lo;
    uint32_t dw[4];
#pragma unroll
    for (int p = 0; p < 4; ++p) {
      const int k = 32 * half + hi * 8 + 2 * p;
      dw[p] = (uint32_t)f2bfu(W[k * 64 + c]) | ((uint32_t)f2bfu(W[(k + 1) * 64 + c]) << 16);
    }
    uint4 q; q.x = dw[0]; q.y = dw[1]; q.z = dw[2]; q.w = dw[3];
    *(uint4*)&sWfrag[f][lane][0] = q;
  }
  __syncthreads();

  const int w  = tid >> 6, l = tid & 63;
  const int lo = l & 15,  hi = l >> 4;
  float*   xb     = &sXp[w][0];
  uint8_t* trbase = (uint8_t*)xb;                 // reuse for bf16 transposes
  const uint32_t swz = (uint32_t)((lo & 7) << 4);

#define WF(m, half, t) (*(const bf16x8*)&sWfrag[(m) * 8 + (half) * 4 + (t)][l][0])

  const int ntiles = (E + 15) >> 4;
  for (int tile = blockIdx.x * WAVES_PER_BLOCK + w; tile < ntiles;
       tile += gridDim.x * WAVES_PER_BLOCK) {
    const int e = tile * 16 + lo;
    const bool valid = e < E;
    const int ec = valid ? e : (E - 1);
    const int src = eidx[ec];
    const int dst = eidx[E + ec];
    const float d0 = pos[dst * 3 + 0] - pos[src * 3 + 0];
    const float d1 = pos[dst * 3 + 1] - pos[src * 3 + 1];
    const float d2 = pos[dst * 3 + 2] - pos[src * 3 + 2];

    // pos layer 1 (3->64) directly in B-frag layout
    bf16x8 hf[2];
#pragma unroll
    for (int half = 0; half < 2; ++half) {
#pragma unroll
      for (int i = 0; i < 8; ++i) {
        const int k = 32 * half + hi * 8 + i;
        float h = sSmall[192 + k] + d0 * sSmall[k] + d1 * sSmall[64 + k] + d2 * sSmall[128 + k];
        hf[half][i] = (short)f2bfu(fmaxf(h, 0.f));
      }
    }
    // pos layer 2 via MFMA
    f32x4 dl[4];
#pragma unroll
    for (int t = 0; t < 4; ++t) {
      f32x4 acc = *(const f32x4*)&sSmall[256 + t * 16 + hi * 4];
      acc = mfma16(WF(0, 0, t), hf[0], acc);
      acc = mfma16(WF(0, 1, t), hf[1], acc);
#pragma unroll
      for (int r = 0; r < 4; ++r) dl[t][r] = fmaxf(acc[r], 0.f);
    }
    // transpose delta -> B-frag layout (bf16, XOR swizzle, wave-private)
    asm volatile("s_waitcnt lgkmcnt(0)" ::: "memory");
#pragma unroll
    for (int t = 0; t < 4; ++t) {
      uint2 p; p.x = pk2(dl[t][0], dl[t][1]); p.y = pk2(dl[t][2], dl[t][3]);
      *(uint2*)(trbase + lo * 128 + (((uint32_t)(t * 32 + hi * 8)) ^ swz)) = p;
    }
    asm volatile("s_waitcnt lgkmcnt(0)" ::: "memory");
    bf16x8 tf[2];
#pragma unroll
    for (int half = 0; half < 2; ++half) {
      bf16x8 dfr = *(const bf16x8*)(trbase + lo * 128 + (((uint32_t)(half * 64 + hi * 16)) ^ swz));
      const int base = 32 * half + hi * 8;
      const f32x4 A0 = *(const f32x4*)&a_dst[(size_t)dst * 64 + base];
      const f32x4 A1 = *(const f32x4*)&a_dst[(size_t)dst * 64 + base + 4];
      const f32x4 S0 = *(const f32x4*)&a_src[(size_t)src * 64 + base];
      const f32x4 S1 = *(const f32x4*)&a_src[(size_t)src * 64 + base + 4];
#pragma unroll
      for (int i = 0; i < 8; ++i) {
        const float av = ((i < 4) ? A0[i] : A1[i - 4]) - ((i < 4) ? S0[i] : S1[i - 4]) + bf2f(dfr[i]);
        tf[half][i] = (short)f2bfu(av);
      }
    }
    // attn layer 1
    f32x4 ga[4];
#pragma unroll
    for (int t = 0; t < 4; ++t) {
      f32x4 acc = *(const f32x4*)&sSmall[320 + t * 16 + hi * 4];
      acc = mfma16(WF(1, 0, t), tf[0], acc);
      acc = mfma16(WF(1, 1, t), tf[1], acc);
#pragma unroll
      for (int r = 0; r < 4; ++r) ga[t][r] = fmaxf(acc[r], 0.f);
    }
    asm volatile("s_waitcnt lgkmcnt(0)" ::: "memory");
#pragma unroll
    for (int t = 0; t < 4; ++t) {
      uint2 p; p.x = pk2(ga[t][0], ga[t][1]); p.y = pk2(ga[t][2], ga[t][3]);
      *(uint2*)(trbase + lo * 128 + (((uint32_t)(t * 32 + hi * 8)) ^ swz)) = p;
    }
    asm volatile("s_waitcnt lgkmcnt(0)" ::: "memory");
    bf16x8 gf0 = *(const bf16x8*)(trbase + lo * 128 + (((uint32_t)(0 * 64 + hi * 16)) ^ swz));
    bf16x8 gf1 = *(const bf16x8*)(trbase + lo * 128 + (((uint32_t)(1 * 64 + hi * 16)) ^ swz));
    // attn layer 2 -> alpha -> ex; keep ex and num-contribution in regs
    f32x4 exv[4], nval[4];
#pragma unroll
    for (int t = 0; t < 4; ++t) {
      f32x4 acc = *(const f32x4*)&sSmall[384 + t * 16 + hi * 4];
      acc = mfma16(WF(2, 0, t), gf0, acc);
      acc = mfma16(WF(2, 1, t), gf1, acc);
      const f32x4 vv = *(const f32x4*)&v[(size_t)src * 64 + t * 16 + hi * 4];
#pragma unroll
      for (int r = 0; r < 4; ++r) {
        const float ex = __expf(fmaxf(acc[r], 0.f));
        exv[t][r] = ex;
        nval[t][r] = ex * (vv[r] + dl[t][r]);
      }
    }
    // ---- coalesced atomic epilogue ----
    if (hi == 0) sDst[w][lo] = dst;
    asm volatile("s_waitcnt lgkmcnt(0)" ::: "memory");   // gf reads done before overwrite
#pragma unroll
    for (int t = 0; t < 4; ++t)
      *(f32x4*)&xb[lo * 68 + t * 16 + hi * 4] = nval[t];
    asm volatile("s_waitcnt lgkmcnt(0)" ::: "memory");
    const int tbase = tile * 16;
#pragma unroll
    for (int ee = 0; ee < 16; ++ee) {
      const int de = sDst[w][ee];
      const float nv = xb[ee * 68 + l];
      if (tbase + ee < E) atomicAdd(&num[(size_t)de * 64 + l], nv);
    }
    asm volatile("s_waitcnt lgkmcnt(0)" ::: "memory");
#pragma unroll
    for (int t = 0; t < 4; ++t)
      *(f32x4*)&xb[lo * 68 + t * 16 + hi * 4] = exv[t];
    asm volatile("s_waitcnt lgkmcnt(0)" ::: "memory");
#pragma unroll
    for (int ee = 0; ee < 16; ++ee) {
      const int de = sDst[w][ee];
      const float dv = xb[ee * 68 + l];
      if (tbase + ee < E) atomicAdd(&den[(size_t)de * 64 + l], dv);
    }
  }
#undef WF
}

// ---------------- node kernels ----------------
__global__ __launch_bounds__(256) void node_in_kernel(
    const float* __restrict__ x, const float* __restrict__ W_in, const float* __restrict__ b_in,
    const float* __restrict__ W_lin, const float* __restrict__ W_src, const float* __restrict__ W_dst,
    float* __restrict__ v, float* __restrict__ a_src, float* __restrict__ a_dst, int N) {
  __shared__ float sW[3 * 4096];
  __shared__ float sb[64];
  __shared__ float xbuf[WAVES_PER_BLOCK][64];
  __shared__ float x1buf[WAVES_PER_BLOCK][64];
  for (int i = threadIdx.x; i < 4096; i += 256) {
    sW[i] = W_in[i]; sW[4096 + i] = W_lin[i]; sW[8192 + i] = W_src[i];
  }
  if (threadIdx.x < 64) sb[threadIdx.x] = b_in[threadIdx.x];
  __syncthreads();
  const int w = threadIdx.x >> 6, c = threadIdx.x & 63;
  const int npi = gridDim.x * WAVES_PER_BLOCK;
  const int iters = (N + npi - 1) / npi;
  for (int it = 0; it < iters; ++it) {
    const int n = it * npi + blockIdx.x * WAVES_PER_BLOCK + w;
    const bool act = n < N;
    xbuf[w][c] = act ? x[n * 64 + c] : 0.f;
    __syncthreads();
    float acc = sb[c];
#pragma unroll
    for (int k = 0; k < 64; ++k) acc += xbuf[w][k] * sW[k * 64 + c];
    x1buf[w][c] = fmaxf(acc, 0.f);
    __syncthreads();
    float av = 0.f, as = 0.f, ad = 0.f;
#pragma unroll
    for (int k = 0; k < 64; ++k) {
      const float xv = x1buf[w][k];
      av += xv * sW[4096 + k * 64 + c];
      as += xv * sW[8192 + k * 64 + c];
      ad += xv * W_dst[k * 64 + c];
    }
    if (act) { v[n * 64 + c] = av; a_src[n * 64 + c] = as; a_dst[n * 64 + c] = ad; }
    __syncthreads();
  }
}

__global__ __launch_bounds__(256) void node_out_kernel(
    const float* __restrict__ num, const float* __restrict__ den,
    const float* __restrict__ W_out, const float* __restrict__ b_out,
    float* __restrict__ out, int N) {
  __shared__ float sW[4096];
  __shared__ float sb[64];
  __shared__ float sbuf[WAVES_PER_BLOCK][64];
  for (int i = threadIdx.x; i < 4096; i += 256) sW[i] = W_out[i];
  if (threadIdx.x < 64) sb[threadIdx.x] = b_out[threadIdx.x];
  __syncthreads();
  const int w = threadIdx.x >> 6, c = threadIdx.x & 63;
  const int npi = gridDim.x * WAVES_PER_BLOCK;
  const int iters = (N + npi - 1) / npi;
  for (int it = 0; it < iters; ++it) {
    const int n = it * npi + blockIdx.x * WAVES_PER_BLOCK + w;
    const bool act = n < N;
    float s = 0.f;
    if (act) {
      const float d = den[n * 64 + c];
      s = num[n * 64 + c] / (d + 1e-16f);
    }
    sbuf[w][c] = s;
    __syncthreads();
    float acc = sb[c];
#pragma unroll
    for (int k = 0; k < 64; ++k) acc += sbuf[w][k] * sW[k * 64 + c];
    if (act) out[n * 64 + c] = fmaxf(acc, 0.f);
    __syncthreads();
  }
}

extern "C" void kernel_launch(void* const* d_in, const int* in_sizes, int n_in,
                              void* d_out, int out_size, void* d_ws, size_t ws_size,
                              hipStream_t stream) {
  const float* x     = (const float*)d_in[0];
  const float* pos   = (const float*)d_in[1];
  const float* W_in  = (const float*)d_in[2];
  const float* b_in  = (const float*)d_in[3];
  const float* W_lin = (const float*)d_in[4];
  const float* W_src = (const float*)d_in[5];
  const float* W_dst = (const float*)d_in[6];
  const float* pW1   = (const float*)d_in[7];
  const float* pb1   = (const float*)d_in[8];
  const float* pW2   = (const float*)d_in[9];
  const float* pb2   = (const float*)d_in[10];
  const float* aW1   = (const float*)d_in[11];
  const float* ab1   = (const float*)d_in[12];
  const float* aW2   = (const float*)d_in[13];
  const float* ab2   = (const float*)d_in[14];
  const float* W_out = (const float*)d_in[15];
  const float* b_out = (const float*)d_in[16];
  const int*   eidx  = (const int*)d_in[17];

  const int N = in_sizes[0] / 64;
  const int E = in_sizes[17] / 2;

  float* ws    = (float*)d_ws;
  float* v     = ws;
  float* a_src = ws + (size_t)1 * N * 64;
  float* a_dst = ws + (size_t)2 * N * 64;
  float* num   = ws + (size_t)3 * N * 64;
  float* den   = ws + (size_t)4 * N * 64;

  hipMemsetAsync(num, 0, (size_t)2 * N * 64 * sizeof(float), stream);

  node_in_kernel<<<1024, 256, 0, stream>>>(x, W_in, b_in, W_lin, W_src, W_dst,
                                           v, a_src, a_dst, N);
  edge_mfma_kernel<<<768, 256, 0, stream>>>(pos, v, a_src, a_dst,
                                            pW1, pb1, pW2, pb2, aW1, ab1, aW2, ab2,
                                            eidx, num, den, E);
  node_out_kernel<<<1024, 256, 0, stream>>>(num, den, W_out, b_out, (float*)d_out, N);
}

// Round 4
// 390.955 us; speedup vs baseline: 3.6861x; 1.1642x over previous
//
#include <hip/hip_runtime.h>
#include <hip/hip_bf16.h>

// Round 4: edge kernel = 512-thread blocks (16 waves/CU), software-pipelined
// gathers (prefetch eidx/pos; hoist a_dst/a_src loads), 4 lgkm drains/tile.
// Node kernels MFMA-ized with the same 16-row-tile template.

using bf16x8 = __attribute__((ext_vector_type(8))) short;
using f32x4  = __attribute__((ext_vector_type(4))) float;

__device__ __forceinline__ uint16_t f2bfu(float f) {
  union { float f; uint32_t u; } v; v.f = f;
  uint32_t r = v.u + 0x7fffu + ((v.u >> 16) & 1u);
  return (uint16_t)(r >> 16);
}
__device__ __forceinline__ float bf2f(short s) {
  union { uint32_t u; float f; } v; v.u = ((uint32_t)(uint16_t)s) << 16;
  return v.f;
}
__device__ __forceinline__ uint32_t pk2(float a, float b) {
  return (uint32_t)f2bfu(a) | ((uint32_t)f2bfu(b) << 16);
}
__device__ __forceinline__ f32x4 mfma16(bf16x8 a, bf16x8 b, f32x4 c) {
  return __builtin_amdgcn_mfma_f32_16x16x32_bf16(a, b, c, 0, 0, 0);
}
#define LGKM0 asm volatile("s_waitcnt lgkmcnt(0)" ::: "memory")

// ================= edge kernel =================
__global__ __launch_bounds__(512, 4) void edge_mfma_kernel(
    const float* __restrict__ pos,
    const float* __restrict__ v, const float* __restrict__ a_src, const float* __restrict__ a_dst,
    const float* __restrict__ pW1, const float* __restrict__ pb1,
    const float* __restrict__ pW2, const float* __restrict__ pb2,
    const float* __restrict__ aW1, const float* __restrict__ ab1,
    const float* __restrict__ aW2, const float* __restrict__ ab2,
    const int* __restrict__ eidx,
    float* __restrict__ num, float* __restrict__ den, int E) {
  __shared__ uint32_t sWfrag[24][64][4];     // 24 KB: pW2, aW1, aW2 A-frags
  __shared__ float    sSmall[448];           // pW1(192) pb1 pb2 ab1 ab2
  __shared__ float    sXp[8][16 * 68];       // 34.8 KB: per-wave scratch
  __shared__ int      sDst[8][16];

  const int tid = threadIdx.x;
  for (int i = tid; i < 448; i += 512) {
    float val;
    if      (i < 192) val = pW1[i];
    else if (i < 256) val = pb1[i - 192];
    else if (i < 320) val = pb2[i - 256];
    else if (i < 384) val = ab1[i - 320];
    else              val = ab2[i - 384];
    sSmall[i] = val;
  }
  for (int idx = tid; idx < 24 * 64; idx += 512) {
    const int f = idx >> 6, lane = idx & 63;
    const int m = f >> 3, half = (f >> 2) & 1, t = f & 3;
    const float* W = (m == 0) ? pW2 : (m == 1) ? aW1 : aW2;
    const int lo = lane & 15, hi = lane >> 4;
    const int c = t * 16 + lo;
    uint32_t dw[4];
#pragma unroll
    for (int p = 0; p < 4; ++p) {
      const int k = 32 * half + hi * 8 + 2 * p;
      dw[p] = (uint32_t)f2bfu(W[k * 64 + c]) | ((uint32_t)f2bfu(W[(k + 1) * 64 + c]) << 16);
    }
    uint4 q; q.x = dw[0]; q.y = dw[1]; q.z = dw[2]; q.w = dw[3];
    *(uint4*)&sWfrag[f][lane][0] = q;
  }
  __syncthreads();

  const int w  = tid >> 6, l = tid & 63;
  const int lo = l & 15,  hi = l >> 4;
  float*   xb     = &sXp[w][0];
  uint8_t* trbase = (uint8_t*)xb;
  const uint32_t swz = (uint32_t)((lo & 7) << 4);
  const int ho = hi * 8;

#define WF(m, half, t) (*(const bf16x8*)&sWfrag[(m) * 8 + (half) * 4 + (t)][l][0])

  const int ntiles = (E + 15) >> 4;
  const int stride = gridDim.x * 8;

  // ---- prologue prefetch (tile 0 for this wave) ----
  int cs = 0, cd = 0; float c0 = 0.f, c1 = 0.f, c2 = 0.f;
  {
    const int t0 = blockIdx.x * 8 + w;
    if (t0 < ntiles) {
      const int ee = t0 * 16 + lo;
      const int ec = ee < E ? ee : (E - 1);
      cs = eidx[ec]; cd = eidx[E + ec];
      c0 = pos[cd * 3 + 0] - pos[cs * 3 + 0];
      c1 = pos[cd * 3 + 1] - pos[cs * 3 + 1];
      c2 = pos[cd * 3 + 2] - pos[cs * 3 + 2];
    }
  }

  for (int tile = blockIdx.x * 8 + w; tile < ntiles; tile += stride) {
    const int src = cs, dst = cd;
    const float d0 = c0, d1 = c1, d2 = c2;
    const bool valid = (tile * 16 + lo) < E;
    const size_t db = (size_t)dst * 64, sb = (size_t)src * 64;

    // ---- issue current tile's row gathers NOW (consumed mid-iteration) ----
    const f32x4 Ad00 = *(const f32x4*)&a_dst[db + ho];
    const f32x4 Ad01 = *(const f32x4*)&a_dst[db + ho + 4];
    const f32x4 Ad10 = *(const f32x4*)&a_dst[db + 32 + ho];
    const f32x4 Ad11 = *(const f32x4*)&a_dst[db + 32 + ho + 4];
    const f32x4 As00 = *(const f32x4*)&a_src[sb + ho];
    const f32x4 As01 = *(const f32x4*)&a_src[sb + ho + 4];
    const f32x4 As10 = *(const f32x4*)&a_src[sb + 32 + ho];
    const f32x4 As11 = *(const f32x4*)&a_src[sb + 32 + ho + 4];

    // ---- prefetch next tile's eidx + pos ----
    const int nt = tile + stride;
    if (nt < ntiles) {
      const int ee = nt * 16 + lo;
      const int ec = ee < E ? ee : (E - 1);
      cs = eidx[ec]; cd = eidx[E + ec];
      c0 = pos[cd * 3 + 0] - pos[cs * 3 + 0];
      c1 = pos[cd * 3 + 1] - pos[cs * 3 + 1];
      c2 = pos[cd * 3 + 2] - pos[cs * 3 + 2];
    }

    if (hi == 0) sDst[w][lo] = dst;

    // ---- pos layer 1 (3->64) in B-frag layout ----
    bf16x8 hf[2];
#pragma unroll
    for (int half = 0; half < 2; ++half) {
#pragma unroll
      for (int i = 0; i < 8; ++i) {
        const int k = 32 * half + hi * 8 + i;
        float h = sSmall[192 + k] + d0 * sSmall[k] + d1 * sSmall[64 + k] + d2 * sSmall[128 + k];
        hf[half][i] = (short)f2bfu(fmaxf(h, 0.f));
      }
    }
    // ---- pos layer 2 ----
    f32x4 dl[4];
#pragma unroll
    for (int t = 0; t < 4; ++t) {
      f32x4 acc = *(const f32x4*)&sSmall[256 + t * 16 + hi * 4];
      acc = mfma16(WF(0, 0, t), hf[0], acc);
      acc = mfma16(WF(0, 1, t), hf[1], acc);
#pragma unroll
      for (int r = 0; r < 4; ++r) dl[t][r] = fmaxf(acc[r], 0.f);
    }
    // ---- transpose delta (region D = [0,2048)) ----
    LGKM0;
#pragma unroll
    for (int t = 0; t < 4; ++t) {
      uint2 p; p.x = pk2(dl[t][0], dl[t][1]); p.y = pk2(dl[t][2], dl[t][3]);
      *(uint2*)(trbase + lo * 128 + (((uint32_t)(t * 32 + hi * 8)) ^ swz)) = p;
    }
    LGKM0;
    const bf16x8 dfr0 = *(const bf16x8*)(trbase + lo * 128 + (((uint32_t)(hi * 16)) ^ swz));
    const bf16x8 dfr1 = *(const bf16x8*)(trbase + lo * 128 + (((uint32_t)(64 + hi * 16)) ^ swz));

    // ---- attn input ----
    bf16x8 tf[2];
#pragma unroll
    for (int i = 0; i < 8; ++i) {
      const float av = ((i < 4) ? Ad00[i] : Ad01[i - 4]) - ((i < 4) ? As00[i] : As01[i - 4]) + bf2f(dfr0[i]);
      tf[0][i] = (short)f2bfu(av);
    }
#pragma unroll
    for (int i = 0; i < 8; ++i) {
      const float av = ((i < 4) ? Ad10[i] : Ad11[i - 4]) - ((i < 4) ? As10[i] : As11[i - 4]) + bf2f(dfr1[i]);
      tf[1][i] = (short)f2bfu(av);
    }

    // ---- issue v gather (needed at the end) ----
    f32x4 V[4];
#pragma unroll
    for (int t = 0; t < 4; ++t) V[t] = *(const f32x4*)&v[sb + t * 16 + hi * 4];

    // ---- attn layer 1 ----
    f32x4 ga[4];
#pragma unroll
    for (int t = 0; t < 4; ++t) {
      f32x4 acc = *(const f32x4*)&sSmall[320 + t * 16 + hi * 4];
      acc = mfma16(WF(1, 0, t), tf[0], acc);
      acc = mfma16(WF(1, 1, t), tf[1], acc);
#pragma unroll
      for (int r = 0; r < 4; ++r) ga[t][r] = fmaxf(acc[r], 0.f);
    }
    // ---- transpose ga (region G = [2048,4096)) ----
#pragma unroll
    for (int t = 0; t < 4; ++t) {
      uint2 p; p.x = pk2(ga[t][0], ga[t][1]); p.y = pk2(ga[t][2], ga[t][3]);
      *(uint2*)(trbase + 2048 + lo * 128 + (((uint32_t)(t * 32 + hi * 8)) ^ swz)) = p;
    }
    LGKM0;
    const bf16x8 gf0 = *(const bf16x8*)(trbase + 2048 + lo * 128 + (((uint32_t)(hi * 16)) ^ swz));
    const bf16x8 gf1 = *(const bf16x8*)(trbase + 2048 + lo * 128 + (((uint32_t)(64 + hi * 16)) ^ swz));

    // ---- attn layer 2 -> ex; write nval to f32 buffer as computed ----
    f32x4 exv[4];
#pragma unroll
    for (int t = 0; t < 4; ++t) {
      f32x4 acc = *(const f32x4*)&sSmall[384 + t * 16 + hi * 4];
      acc = mfma16(WF(2, 0, t), gf0, acc);
      acc = mfma16(WF(2, 1, t), gf1, acc);
      f32x4 nv;
#pragma unroll
      for (int r = 0; r < 4; ++r) {
        const float ex = __expf(fmaxf(acc[r], 0.f));
        exv[t][r] = ex;
        nv[r] = ex * (V[t][r] + dl[t][r]);
      }
      *(f32x4*)&xb[lo * 68 + t * 16 + hi * 4] = nv;
    }
    LGKM0;
    const int tbase = tile * 16;
#pragma unroll
    for (int ee = 0; ee < 16; ++ee) {
      const int de = sDst[w][ee];
      const float nv = xb[ee * 68 + l];
      if (tbase + ee < E) atomicAdd(&num[(size_t)de * 64 + l], nv);
    }
#pragma unroll
    for (int t = 0; t < 4; ++t)
      *(f32x4*)&xb[lo * 68 + t * 16 + hi * 4] = exv[t];
    LGKM0;
#pragma unroll
    for (int ee = 0; ee < 16; ++ee) {
      const int de = sDst[w][ee];
      const float dv = xb[ee * 68 + l];
      if (tbase + ee < E) atomicAdd(&den[(size_t)de * 64 + l], dv);
    }
    (void)valid;
  }
#undef WF
}

// ================= node_in (MFMA) =================
__global__ __launch_bounds__(256, 4) void node_in_mfma(
    const float* __restrict__ x, const float* __restrict__ W_in, const float* __restrict__ b_in,
    const float* __restrict__ W_lin, const float* __restrict__ W_src, const float* __restrict__ W_dst,
    float* __restrict__ v, float* __restrict__ a_src, float* __restrict__ a_dst, int N) {
  __shared__ uint32_t sWfrag[32][64][4];   // 32 KB: W_in, W_lin, W_src, W_dst
  __shared__ float    sBias[64];
  __shared__ float    sXp[4][16 * 68];     // 17.4 KB

  const int tid = threadIdx.x;
  for (int idx = tid; idx < 32 * 64; idx += 256) {
    const int f = idx >> 6, lane = idx & 63;
    const int m = f >> 3, half = (f >> 2) & 1, t = f & 3;
    const float* W = (m == 0) ? W_in : (m == 1) ? W_lin : (m == 2) ? W_src : W_dst;
    const int lo = lane & 15, hi = lane >> 4;
    const int c = t * 16 + lo;
    uint32_t dw[4];
#pragma unroll
    for (int p = 0; p < 4; ++p) {
      const int k = 32 * half + hi * 8 + 2 * p;
      dw[p] = (uint32_t)f2bfu(W[k * 64 + c]) | ((uint32_t)f2bfu(W[(k + 1) * 64 + c]) << 16);
    }
    uint4 q; q.x = dw[0]; q.y = dw[1]; q.z = dw[2]; q.w = dw[3];
    *(uint4*)&sWfrag[f][lane][0] = q;
  }
  if (tid < 64) sBias[tid] = b_in[tid];
  __syncthreads();

  const int w  = tid >> 6, l = tid & 63;
  const int lo = l & 15,  hi = l >> 4;
  float*   xb     = &sXp[w][0];
  uint8_t* trbase = (uint8_t*)xb;
  const uint32_t swz = (uint32_t)((lo & 7) << 4);

#define WF(m, half, t) (*(const bf16x8*)&sWfrag[(m) * 8 + (half) * 4 + (t)][l][0])

  const int ntiles = (N + 15) >> 4;
  for (int tile = blockIdx.x * 4 + w; tile < ntiles; tile += gridDim.x * 4) {
    const int row = tile * 16 + lo;
    const int rowc = row < N ? row : (N - 1);
    bf16x8 xf[2];
#pragma unroll
    for (int half = 0; half < 2; ++half) {
      const int base = 32 * half + hi * 8;
      const f32x4 X0 = *(const f32x4*)&x[(size_t)rowc * 64 + base];
      const f32x4 X1 = *(const f32x4*)&x[(size_t)rowc * 64 + base + 4];
#pragma unroll
      for (int i = 0; i < 8; ++i)
        xf[half][i] = (short)f2bfu((i < 4) ? X0[i] : X1[i - 4]);
    }
    // x1 = relu(W_in^T X + b)
    f32x4 x1[4];
#pragma unroll
    for (int t = 0; t < 4; ++t) {
      f32x4 acc = *(const f32x4*)&sBias[t * 16 + hi * 4];
      acc = mfma16(WF(0, 0, t), xf[0], acc);
      acc = mfma16(WF(0, 1, t), xf[1], acc);
#pragma unroll
      for (int r = 0; r < 4; ++r) x1[t][r] = fmaxf(acc[r], 0.f);
    }
    // transpose x1 -> B-frag
    LGKM0;
#pragma unroll
    for (int t = 0; t < 4; ++t) {
      uint2 p; p.x = pk2(x1[t][0], x1[t][1]); p.y = pk2(x1[t][2], x1[t][3]);
      *(uint2*)(trbase + lo * 128 + (((uint32_t)(t * 32 + hi * 8)) ^ swz)) = p;
    }
    LGKM0;
    const bf16x8 x1f0 = *(const bf16x8*)(trbase + lo * 128 + (((uint32_t)(hi * 16)) ^ swz));
    const bf16x8 x1f1 = *(const bf16x8*)(trbase + lo * 128 + (((uint32_t)(64 + hi * 16)) ^ swz));

    // three projections
#pragma unroll
    for (int m = 1; m <= 3; ++m) {
      f32x4 res[4];
#pragma unroll
      for (int t = 0; t < 4; ++t) {
        f32x4 acc = {0.f, 0.f, 0.f, 0.f};
        acc = mfma16(WF(m, 0, t), x1f0, acc);
        acc = mfma16(WF(m, 1, t), x1f1, acc);
        res[t] = acc;
      }
#pragma unroll
      for (int t = 0; t < 4; ++t)
        *(f32x4*)&xb[lo * 68 + t * 16 + hi * 4] = res[t];
      LGKM0;
      float* out = (m == 1) ? v : (m == 2) ? a_src : a_dst;
#pragma unroll
      for (int ee = 0; ee < 16; ++ee) {
        const int r2 = tile * 16 + ee;
        if (r2 < N) out[(size_t)r2 * 64 + l] = xb[ee * 68 + l];
      }
      LGKM0;   // reads done before next m overwrites
    }
  }
#undef WF
}

// ================= node_out (MFMA) =================
__global__ __launch_bounds__(512, 4) void node_out_mfma(
    const float* __restrict__ num, const float* __restrict__ den,
    const float* __restrict__ W_out, const float* __restrict__ b_out,
    float* __restrict__ out, int N) {
  __shared__ uint32_t sWfrag[8][64][4];   // 8 KB
  __shared__ float    sBias[64];
  __shared__ float    sXp[8][16 * 68];    // 34.8 KB

  const int tid = threadIdx.x;
  for (int idx = tid; idx < 8 * 64; idx += 512) {
    const int f = idx >> 6, lane = idx & 63;
    const int half = (f >> 2) & 1, t = f & 3;
    const int lo = lane & 15, hi = lane >> 4;
    const int c = t * 16 + lo;
    uint32_t dw[4];
#pragma unroll
    for (int p = 0; p < 4; ++p) {
      const int k = 32 * half + hi * 8 + 2 * p;
      dw[p] = (uint32_t)f2bfu(W_out[k * 64 + c]) | ((uint32_t)f2bfu(W_out[(k + 1) * 64 + c]) << 16);
    }
    uint4 q; q.x = dw[0]; q.y = dw[1]; q.z = dw[2]; q.w = dw[3];
    *(uint4*)&sWfrag[f][lane][0] = q;
  }
  if (tid < 64) sBias[tid] = b_out[tid];
  __syncthreads();

  const int w  = tid >> 6, l = tid & 63;
  const int lo = l & 15,  hi = l >> 4;
  float* xb = &sXp[w][0];

#define WFo(half, t) (*(const bf16x8*)&sWfrag[(half) * 4 + (t)][l][0])

  const int ntiles = (N + 15) >> 4;
  for (int tile = blockIdx.x * 8 + w; tile < ntiles; tile += gridDim.x * 8) {
    const int row = tile * 16 + lo;
    const int rowc = row < N ? row : (N - 1);
    bf16x8 sf[2];
#pragma unroll
    for (int half = 0; half < 2; ++half) {
      const int base = 32 * half + hi * 8;
      const f32x4 N0 = *(const f32x4*)&num[(size_t)rowc * 64 + base];
      const f32x4 N1 = *(const f32x4*)&num[(size_t)rowc * 64 + base + 4];
      const f32x4 D0 = *(const f32x4*)&den[(size_t)rowc * 64 + base];
      const f32x4 D1 = *(const f32x4*)&den[(size_t)rowc * 64 + base + 4];
#pragma unroll
      for (int i = 0; i < 8; ++i) {
        const float nn = (i < 4) ? N0[i] : N1[i - 4];
        const float dd = (i < 4) ? D0[i] : D1[i - 4];
        sf[half][i] = (short)f2bfu(nn / (dd + 1e-16f));
      }
    }
    f32x4 res[4];
#pragma unroll
    for (int t = 0; t < 4; ++t) {
      f32x4 acc = *(const f32x4*)&sBias[t * 16 + hi * 4];
      acc = mfma16(WFo(0, t), sf[0], acc);
      acc = mfma16(WFo(1, t), sf[1], acc);
#pragma unroll
      for (int r = 0; r < 4; ++r) res[t][r] = fmaxf(acc[r], 0.f);
    }
    LGKM0;
#pragma unroll
    for (int t = 0; t < 4; ++t)
      *(f32x4*)&xb[lo * 68 + t * 16 + hi * 4] = res[t];
    LGKM0;
#pragma unroll
    for (int ee = 0; ee < 16; ++ee) {
      const int r2 = tile * 16 + ee;
      if (r2 < N) out[(size_t)r2 * 64 + l] = xb[ee * 68 + l];
    }
  }
#undef WFo
}

extern "C" void kernel_launch(void* const* d_in, const int* in_sizes, int n_in,
                              void* d_out, int out_size, void* d_ws, size_t ws_size,
                              hipStream_t stream) {
  const float* x     = (const float*)d_in[0];
  const float* pos   = (const float*)d_in[1];
  const float* W_in  = (const float*)d_in[2];
  const float* b_in  = (const float*)d_in[3];
  const float* W_lin = (const float*)d_in[4];
  const float* W_src = (const float*)d_in[5];
  const float* W_dst = (const float*)d_in[6];
  const float* pW1   = (const float*)d_in[7];
  const float* pb1   = (const float*)d_in[8];
  const float* pW2   = (const float*)d_in[9];
  const float* pb2   = (const float*)d_in[10];
  const float* aW1   = (const float*)d_in[11];
  const float* ab1   = (const float*)d_in[12];
  const float* aW2   = (const float*)d_in[13];
  const float* ab2   = (const float*)d_in[14];
  const float* W_out = (const float*)d_in[15];
  const float* b_out = (const float*)d_in[16];
  const int*   eidx  = (const int*)d_in[17];

  const int N = in_sizes[0] / 64;
  const int E = in_sizes[17] / 2;

  float* ws    = (float*)d_ws;
  float* v     = ws;
  float* a_src = ws + (size_t)1 * N * 64;
  float* a_dst = ws + (size_t)2 * N * 64;
  float* num   = ws + (size_t)3 * N * 64;
  float* den   = ws + (size_t)4 * N * 64;

  hipMemsetAsync(num, 0, (size_t)2 * N * 64 * sizeof(float), stream);

  node_in_mfma<<<784, 256, 0, stream>>>(x, W_in, b_in, W_lin, W_src, W_dst,
                                        v, a_src, a_dst, N);
  edge_mfma_kernel<<<512, 512, 0, stream>>>(pos, v, a_src, a_dst,
                                            pW1, pb1, pW2, pb2, aW1, ab1, aW2, ab2,
                                            eidx, num, den, E);
  node_out_mfma<<<392, 512, 0, stream>>>(num, den, W_out, b_out, (float*)d_out, N);
}

// Round 5
// 307.188 us; speedup vs baseline: 4.6913x; 1.2727x over previous
//
#include <hip/hip_runtime.h>
#include <hip/hip_bf16.h>

// Round 5: dst-grouped edge processing.
//   hist -> scan -> scatter builds dst-sorted packed edges ((dst<<16)|src).
//   Edge kernel run-length-accumulates num/den per dst in registers and
//   flushes once per distinct dst (atomic traffic ~8x lower, a_dst broadcast).

using bf16x8 = __attribute__((ext_vector_type(8))) short;
using f32x4  = __attribute__((ext_vector_type(4))) float;

__device__ __forceinline__ uint16_t f2bfu(float f) {
  union { float f; uint32_t u; } v; v.f = f;
  uint32_t r = v.u + 0x7fffu + ((v.u >> 16) & 1u);
  return (uint16_t)(r >> 16);
}
__device__ __forceinline__ float bf2f(short s) {
  union { uint32_t u; float f; } v; v.u = ((uint32_t)(uint16_t)s) << 16;
  return v.f;
}
__device__ __forceinline__ uint32_t pk2(float a, float b) {
  return (uint32_t)f2bfu(a) | ((uint32_t)f2bfu(b) << 16);
}
__device__ __forceinline__ f32x4 mfma16(bf16x8 a, bf16x8 b, f32x4 c) {
  return __builtin_amdgcn_mfma_f32_16x16x32_bf16(a, b, c, 0, 0, 0);
}
#define LGKM0 asm volatile("s_waitcnt lgkmcnt(0)" ::: "memory")

// ================= sort kernels =================
__global__ __launch_bounds__(256) void hist_kernel(
    const int* __restrict__ eidx, int* __restrict__ cursor, int E) {
  const int e = blockIdx.x * 256 + threadIdx.x;
  if (e < E) atomicAdd(&cursor[eidx[E + e]], 1);
}

__global__ __launch_bounds__(1024) void scan_kernel(int* __restrict__ cursor, int N) {
  __shared__ int sSum[1024];
  const int t = threadIdx.x;
  const int M = (N + 1023) >> 10;
  const int lo = t * M;
  const int hi = min(lo + M, N);
  int s = 0;
  for (int i = lo; i < hi; ++i) s += cursor[i];
  sSum[t] = s;
  __syncthreads();
  for (int off = 1; off < 1024; off <<= 1) {
    const int val = (t >= off) ? sSum[t - off] : 0;
    __syncthreads();
    sSum[t] += val;
    __syncthreads();
  }
  int run = (t == 0) ? 0 : sSum[t - 1];
  for (int i = lo; i < hi; ++i) {
    const int c = cursor[i];
    cursor[i] = run;
    run += c;
  }
}

__global__ __launch_bounds__(256) void scatter_kernel(
    const int* __restrict__ eidx, int* __restrict__ cursor,
    uint32_t* __restrict__ sorted, int E) {
  const int e = blockIdx.x * 256 + threadIdx.x;
  if (e < E) {
    const int s = eidx[e];
    const int d = eidx[E + e];
    const int slot = atomicAdd(&cursor[d], 1);
    sorted[slot] = ((uint32_t)d << 16) | (uint32_t)s;
  }
}

// ================= edge kernel =================
__global__ __launch_bounds__(512, 4) void edge_mfma_kernel(
    const float* __restrict__ pos,
    const float* __restrict__ v, const float* __restrict__ a_src, const float* __restrict__ a_dst,
    const float* __restrict__ pW1, const float* __restrict__ pb1,
    const float* __restrict__ pW2, const float* __restrict__ pb2,
    const float* __restrict__ aW1, const float* __restrict__ ab1,
    const float* __restrict__ aW2, const float* __restrict__ ab2,
    const uint32_t* __restrict__ sorted,
    float* __restrict__ num, float* __restrict__ den, int E) {
  __shared__ uint32_t sWfrag[24][64][4];     // 24 KB
  __shared__ float    sSmall[448];
  __shared__ float    sXp[8][16 * 68];       // 34.8 KB
  __shared__ int      sDst[8][16];

  const int tid = threadIdx.x;
  for (int i = tid; i < 448; i += 512) {
    float val;
    if      (i < 192) val = pW1[i];
    else if (i < 256) val = pb1[i - 192];
    else if (i < 320) val = pb2[i - 256];
    else if (i < 384) val = ab1[i - 320];
    else              val = ab2[i - 384];
    sSmall[i] = val;
  }
  for (int idx = tid; idx < 24 * 64; idx += 512) {
    const int f = idx >> 6, lane = idx & 63;
    const int m = f >> 3, half = (f >> 2) & 1, t = f & 3;
    const float* W = (m == 0) ? pW2 : (m == 1) ? aW1 : aW2;
    const int lo = lane & 15, hi = lane >> 4;
    const int c = t * 16 + lo;
    uint32_t dw[4];
#pragma unroll
    for (int p = 0; p < 4; ++p) {
      const int k = 32 * half + hi * 8 + 2 * p;
      dw[p] = (uint32_t)f2bfu(W[k * 64 + c]) | ((uint32_t)f2bfu(W[(k + 1) * 64 + c]) << 16);
    }
    uint4 q; q.x = dw[0]; q.y = dw[1]; q.z = dw[2]; q.w = dw[3];
    *(uint4*)&sWfrag[f][lane][0] = q;
  }
  __syncthreads();

  const int w  = tid >> 6, l = tid & 63;
  const int lo = l & 15,  hi = l >> 4;
  float*   xb     = &sXp[w][0];
  uint8_t* trbase = (uint8_t*)xb;
  const uint32_t swz = (uint32_t)((lo & 7) << 4);
  const int ho = hi * 8;

#define WF(m, half, t) (*(const bf16x8*)&sWfrag[(m) * 8 + (half) * 4 + (t)][l][0])

  const int ntiles = (E + 15) >> 4;
  const int stride = gridDim.x * 8;

  int cs = 0, cd = 0; float c0 = 0.f, c1 = 0.f, c2 = 0.f;
  {
    const int t0 = blockIdx.x * 8 + w;
    if (t0 < ntiles) {
      const int ee = t0 * 16 + lo;
      const int ec = ee < E ? ee : (E - 1);
      const uint32_t se = sorted[ec];
      cs = (int)(se & 0xFFFFu); cd = (int)(se >> 16);
      c0 = pos[cd * 3 + 0] - pos[cs * 3 + 0];
      c1 = pos[cd * 3 + 1] - pos[cs * 3 + 1];
      c2 = pos[cd * 3 + 2] - pos[cs * 3 + 2];
    }
  }

  for (int tile = blockIdx.x * 8 + w; tile < ntiles; tile += stride) {
    const int src = cs, dst = cd;
    const float d0 = c0, d1 = c1, d2 = c2;
    const size_t db = (size_t)dst * 64, sb = (size_t)src * 64;

    // current tile's row gathers (a_dst is ~broadcast across the tile now)
    const f32x4 Ad00 = *(const f32x4*)&a_dst[db + ho];
    const f32x4 Ad01 = *(const f32x4*)&a_dst[db + ho + 4];
    const f32x4 Ad10 = *(const f32x4*)&a_dst[db + 32 + ho];
    const f32x4 Ad11 = *(const f32x4*)&a_dst[db + 32 + ho + 4];
    const f32x4 As00 = *(const f32x4*)&a_src[sb + ho];
    const f32x4 As01 = *(const f32x4*)&a_src[sb + ho + 4];
    const f32x4 As10 = *(const f32x4*)&a_src[sb + 32 + ho];
    const f32x4 As11 = *(const f32x4*)&a_src[sb + 32 + ho + 4];

    // prefetch next tile
    const int nt = tile + stride;
    if (nt < ntiles) {
      const int ee = nt * 16 + lo;
      const int ec = ee < E ? ee : (E - 1);
      const uint32_t se = sorted[ec];
      cs = (int)(se & 0xFFFFu); cd = (int)(se >> 16);
      c0 = pos[cd * 3 + 0] - pos[cs * 3 + 0];
      c1 = pos[cd * 3 + 1] - pos[cs * 3 + 1];
      c2 = pos[cd * 3 + 2] - pos[cs * 3 + 2];
    }

    if (hi == 0) sDst[w][lo] = dst;

    // pos layer 1 (3->64)
    bf16x8 hf[2];
#pragma unroll
    for (int half = 0; half < 2; ++half) {
#pragma unroll
      for (int i = 0; i < 8; ++i) {
        const int k = 32 * half + hi * 8 + i;
        float h = sSmall[192 + k] + d0 * sSmall[k] + d1 * sSmall[64 + k] + d2 * sSmall[128 + k];
        hf[half][i] = (short)f2bfu(fmaxf(h, 0.f));
      }
    }
    // pos layer 2
    f32x4 dl[4];
#pragma unroll
    for (int t = 0; t < 4; ++t) {
      f32x4 acc = *(const f32x4*)&sSmall[256 + t * 16 + hi * 4];
      acc = mfma16(WF(0, 0, t), hf[0], acc);
      acc = mfma16(WF(0, 1, t), hf[1], acc);
#pragma unroll
      for (int r = 0; r < 4; ++r) dl[t][r] = fmaxf(acc[r], 0.f);
    }
    // transpose delta
    LGKM0;
#pragma unroll
    for (int t = 0; t < 4; ++t) {
      uint2 p; p.x = pk2(dl[t][0], dl[t][1]); p.y = pk2(dl[t][2], dl[t][3]);
      *(uint2*)(trbase + lo * 128 + (((uint32_t)(t * 32 + hi * 8)) ^ swz)) = p;
    }
    LGKM0;
    const bf16x8 dfr0 = *(const bf16x8*)(trbase + lo * 128 + (((uint32_t)(hi * 16)) ^ swz));
    const bf16x8 dfr1 = *(const bf16x8*)(trbase + lo * 128 + (((uint32_t)(64 + hi * 16)) ^ swz));

    bf16x8 tf[2];
#pragma unroll
    for (int i = 0; i < 8; ++i) {
      const float av = ((i < 4) ? Ad00[i] : Ad01[i - 4]) - ((i < 4) ? As00[i] : As01[i - 4]) + bf2f(dfr0[i]);
      tf[0][i] = (short)f2bfu(av);
    }
#pragma unroll
    for (int i = 0; i < 8; ++i) {
      const float av = ((i < 4) ? Ad10[i] : Ad11[i - 4]) - ((i < 4) ? As10[i] : As11[i - 4]) + bf2f(dfr1[i]);
      tf[1][i] = (short)f2bfu(av);
    }

    f32x4 V[4];
#pragma unroll
    for (int t = 0; t < 4; ++t) V[t] = *(const f32x4*)&v[sb + t * 16 + hi * 4];

    // attn layer 1
    f32x4 ga[4];
#pragma unroll
    for (int t = 0; t < 4; ++t) {
      f32x4 acc = *(const f32x4*)&sSmall[320 + t * 16 + hi * 4];
      acc = mfma16(WF(1, 0, t), tf[0], acc);
      acc = mfma16(WF(1, 1, t), tf[1], acc);
#pragma unroll
      for (int r = 0; r < 4; ++r) ga[t][r] = fmaxf(acc[r], 0.f);
    }
#pragma unroll
    for (int t = 0; t < 4; ++t) {
      uint2 p; p.x = pk2(ga[t][0], ga[t][1]); p.y = pk2(ga[t][2], ga[t][3]);
      *(uint2*)(trbase + 2048 + lo * 128 + (((uint32_t)(t * 32 + hi * 8)) ^ swz)) = p;
    }
    LGKM0;
    const bf16x8 gf0 = *(const bf16x8*)(trbase + 2048 + lo * 128 + (((uint32_t)(hi * 16)) ^ swz));
    const bf16x8 gf1 = *(const bf16x8*)(trbase + 2048 + lo * 128 + (((uint32_t)(64 + hi * 16)) ^ swz));

    // attn layer 2 -> ex
    f32x4 exv[4];
#pragma unroll
    for (int t = 0; t < 4; ++t) {
      f32x4 acc = *(const f32x4*)&sSmall[384 + t * 16 + hi * 4];
      acc = mfma16(WF(2, 0, t), gf0, acc);
      acc = mfma16(WF(2, 1, t), gf1, acc);
      f32x4 nv;
#pragma unroll
      for (int r = 0; r < 4; ++r) {
        const float ex = __expf(fmaxf(acc[r], 0.f));
        exv[t][r] = ex;
        nv[r] = ex * (V[t][r] + dl[t][r]);
      }
      *(f32x4*)&xb[lo * 68 + t * 16 + hi * 4] = nv;
    }
    LGKM0;
    const int tbase = tile * 16;
    // ---- pass 1: num, run-length accumulate over equal dst ----
    {
      int run_d = __builtin_amdgcn_readfirstlane(sDst[w][0]);
      float acc = 0.f;
#pragma unroll
      for (int ee = 0; ee < 16; ++ee) {
        if (tbase + ee < E) {
          const int de = __builtin_amdgcn_readfirstlane(sDst[w][ee]);
          const float nv = xb[ee * 68 + l];
          if (de != run_d) {
            atomicAdd(&num[(size_t)run_d * 64 + l], acc);
            run_d = de; acc = 0.f;
          }
          acc += nv;
        }
      }
      atomicAdd(&num[(size_t)run_d * 64 + l], acc);
    }
    // ---- pass 2: den ----
#pragma unroll
    for (int t = 0; t < 4; ++t)
      *(f32x4*)&xb[lo * 68 + t * 16 + hi * 4] = exv[t];
    LGKM0;
    {
      int run_d = __builtin_amdgcn_readfirstlane(sDst[w][0]);
      float acc = 0.f;
#pragma unroll
      for (int ee = 0; ee < 16; ++ee) {
        if (tbase + ee < E) {
          const int de = __builtin_amdgcn_readfirstlane(sDst[w][ee]);
          const float dv = xb[ee * 68 + l];
          if (de != run_d) {
            atomicAdd(&den[(size_t)run_d * 64 + l], acc);
            run_d = de; acc = 0.f;
          }
          acc += dv;
        }
      }
      atomicAdd(&den[(size_t)run_d * 64 + l], acc);
    }
  }
#undef WF
}

// ================= node_in (MFMA) =================
__global__ __launch_bounds__(256, 4) void node_in_mfma(
    const float* __restrict__ x, const float* __restrict__ W_in, const float* __restrict__ b_in,
    const float* __restrict__ W_lin, const float* __restrict__ W_src, const float* __restrict__ W_dst,
    float* __restrict__ v, float* __restrict__ a_src, float* __restrict__ a_dst, int N) {
  __shared__ uint32_t sWfrag[32][64][4];
  __shared__ float    sBias[64];
  __shared__ float    sXp[4][16 * 68];

  const int tid = threadIdx.x;
  for (int idx = tid; idx < 32 * 64; idx += 256) {
    const int f = idx >> 6, lane = idx & 63;
    const int m = f >> 3, half = (f >> 2) & 1, t = f & 3;
    const float* W = (m == 0) ? W_in : (m == 1) ? W_lin : (m == 2) ? W_src : W_dst;
    const int lo = lane & 15, hi = lane >> 4;
    const int c = t * 16 + lo;
    uint32_t dw[4];
#pragma unroll
    for (int p = 0; p < 4; ++p) {
      const int k = 32 * half + hi * 8 + 2 * p;
      dw[p] = (uint32_t)f2bfu(W[k * 64 + c]) | ((uint32_t)f2bfu(W[(k + 1) * 64 + c]) << 16);
    }
    uint4 q; q.x = dw[0]; q.y = dw[1]; q.z = dw[2]; q.w = dw[3];
    *(uint4*)&sWfrag[f][lane][0] = q;
  }
  if (tid < 64) sBias[tid] = b_in[tid];
  __syncthreads();

  const int w  = tid >> 6, l = tid & 63;
  const int lo = l & 15,  hi = l >> 4;
  float*   xb     = &sXp[w][0];
  uint8_t* trbase = (uint8_t*)xb;
  const uint32_t swz = (uint32_t)((lo & 7) << 4);

#define WF(m, half, t) (*(const bf16x8*)&sWfrag[(m) * 8 + (half) * 4 + (t)][l][0])

  const int ntiles = (N + 15) >> 4;
  for (int tile = blockIdx.x * 4 + w; tile < ntiles; tile += gridDim.x * 4) {
    const int row = tile * 16 + lo;
    const int rowc = row < N ? row : (N - 1);
    bf16x8 xf[2];
#pragma unroll
    for (int half = 0; half < 2; ++half) {
      const int base = 32 * half + hi * 8;
      const f32x4 X0 = *(const f32x4*)&x[(size_t)rowc * 64 + base];
      const f32x4 X1 = *(const f32x4*)&x[(size_t)rowc * 64 + base + 4];
#pragma unroll
      for (int i = 0; i < 8; ++i)
        xf[half][i] = (short)f2bfu((i < 4) ? X0[i] : X1[i - 4]);
    }
    f32x4 x1[4];
#pragma unroll
    for (int t = 0; t < 4; ++t) {
      f32x4 acc = *(const f32x4*)&sBias[t * 16 + hi * 4];
      acc = mfma16(WF(0, 0, t), xf[0], acc);
      acc = mfma16(WF(0, 1, t), xf[1], acc);
#pragma unroll
      for (int r = 0; r < 4; ++r) x1[t][r] = fmaxf(acc[r], 0.f);
    }
    LGKM0;
#pragma unroll
    for (int t = 0; t < 4; ++t) {
      uint2 p; p.x = pk2(x1[t][0], x1[t][1]); p.y = pk2(x1[t][2], x1[t][3]);
      *(uint2*)(trbase + lo * 128 + (((uint32_t)(t * 32 + hi * 8)) ^ swz)) = p;
    }
    LGKM0;
    const bf16x8 x1f0 = *(const bf16x8*)(trbase + lo * 128 + (((uint32_t)(hi * 16)) ^ swz));
    const bf16x8 x1f1 = *(const bf16x8*)(trbase + lo * 128 + (((uint32_t)(64 + hi * 16)) ^ swz));

#pragma unroll
    for (int m = 1; m <= 3; ++m) {
      f32x4 res[4];
#pragma unroll
      for (int t = 0; t < 4; ++t) {
        f32x4 acc = {0.f, 0.f, 0.f, 0.f};
        acc = mfma16(WF(m, 0, t), x1f0, acc);
        acc = mfma16(WF(m, 1, t), x1f1, acc);
        res[t] = acc;
      }
#pragma unroll
      for (int t = 0; t < 4; ++t)
        *(f32x4*)&xb[lo * 68 + t * 16 + hi * 4] = res[t];
      LGKM0;
      float* out = (m == 1) ? v : (m == 2) ? a_src : a_dst;
#pragma unroll
      for (int ee = 0; ee < 16; ++ee) {
        const int r2 = tile * 16 + ee;
        if (r2 < N) out[(size_t)r2 * 64 + l] = xb[ee * 68 + l];
      }
      LGKM0;
    }
  }
#undef WF
}

// ================= node_out (MFMA) =================
__global__ __launch_bounds__(512, 4) void node_out_mfma(
    const float* __restrict__ num, const float* __restrict__ den,
    const float* __restrict__ W_out, const float* __restrict__ b_out,
    float* __restrict__ out, int N) {
  __shared__ uint32_t sWfrag[8][64][4];
  __shared__ float    sBias[64];
  __shared__ float    sXp[8][16 * 68];

  const int tid = threadIdx.x;
  for (int idx = tid; idx < 8 * 64; idx += 512) {
    const int f = idx >> 6, lane = idx & 63;
    const int half = (f >> 2) & 1, t = f & 3;
    const int lo = lane & 15, hi = lane >> 4;
    const int c = t * 16 + lo;
    uint32_t dw[4];
#pragma unroll
    for (int p = 0; p < 4; ++p) {
      const int k = 32 * half + hi * 8 + 2 * p;
      dw[p] = (uint32_t)f2bfu(W_out[k * 64 + c]) | ((uint32_t)f2bfu(W_out[(k + 1) * 64 + c]) << 16);
    }
    uint4 q; q.x = dw[0]; q.y = dw[1]; q.z = dw[2]; q.w = dw[3];
    *(uint4*)&sWfrag[f][lane][0] = q;
  }
  if (tid < 64) sBias[tid] = b_out[tid];
  __syncthreads();

  const int w  = tid >> 6, l = tid & 63;
  const int lo = l & 15,  hi = l >> 4;
  float* xb = &sXp[w][0];

#define WFo(half, t) (*(const bf16x8*)&sWfrag[(half) * 4 + (t)][l][0])

  const int ntiles = (N + 15) >> 4;
  for (int tile = blockIdx.x * 8 + w; tile < ntiles; tile += gridDim.x * 8) {
    const int row = tile * 16 + lo;
    const int rowc = row < N ? row : (N - 1);
    bf16x8 sf[2];
#pragma unroll
    for (int half = 0; half < 2; ++half) {
      const int base = 32 * half + hi * 8;
      const f32x4 N0 = *(const f32x4*)&num[(size_t)rowc * 64 + base];
      const f32x4 N1 = *(const f32x4*)&num[(size_t)rowc * 64 + base + 4];
      const f32x4 D0 = *(const f32x4*)&den[(size_t)rowc * 64 + base];
      const f32x4 D1 = *(const f32x4*)&den[(size_t)rowc * 64 + base + 4];
#pragma unroll
      for (int i = 0; i < 8; ++i) {
        const float nn = (i < 4) ? N0[i] : N1[i - 4];
        const float dd = (i < 4) ? D0[i] : D1[i - 4];
        sf[half][i] = (short)f2bfu(nn / (dd + 1e-16f));
      }
    }
    f32x4 res[4];
#pragma unroll
    for (int t = 0; t < 4; ++t) {
      f32x4 acc = *(const f32x4*)&sBias[t * 16 + hi * 4];
      acc = mfma16(WFo(0, t), sf[0], acc);
      acc = mfma16(WFo(1, t), sf[1], acc);
#pragma unroll
      for (int r = 0; r < 4; ++r) res[t][r] = fmaxf(acc[r], 0.f);
    }
    LGKM0;
#pragma unroll
    for (int t = 0; t < 4; ++t)
      *(f32x4*)&xb[lo * 68 + t * 16 + hi * 4] = res[t];
    LGKM0;
#pragma unroll
    for (int ee = 0; ee < 16; ++ee) {
      const int r2 = tile * 16 + ee;
      if (r2 < N) out[(size_t)r2 * 64 + l] = xb[ee * 68 + l];
    }
  }
#undef WFo
}

extern "C" void kernel_launch(void* const* d_in, const int* in_sizes, int n_in,
                              void* d_out, int out_size, void* d_ws, size_t ws_size,
                              hipStream_t stream) {
  const float* x     = (const float*)d_in[0];
  const float* pos   = (const float*)d_in[1];
  const float* W_in  = (const float*)d_in[2];
  const float* b_in  = (const float*)d_in[3];
  const float* W_lin = (const float*)d_in[4];
  const float* W_src = (const float*)d_in[5];
  const float* W_dst = (const float*)d_in[6];
  const float* pW1   = (const float*)d_in[7];
  const float* pb1   = (const float*)d_in[8];
  const float* pW2   = (const float*)d_in[9];
  const float* pb2   = (const float*)d_in[10];
  const float* aW1   = (const float*)d_in[11];
  const float* ab1   = (const float*)d_in[12];
  const float* aW2   = (const float*)d_in[13];
  const float* ab2   = (const float*)d_in[14];
  const float* W_out = (const float*)d_in[15];
  const float* b_out = (const float*)d_in[16];
  const int*   eidx  = (const int*)d_in[17];

  const int N = in_sizes[0] / 64;
  const int E = in_sizes[17] / 2;

  float* ws    = (float*)d_ws;
  float* v     = ws;
  float* a_src = ws + (size_t)1 * N * 64;
  float* a_dst = ws + (size_t)2 * N * 64;
  float* num   = ws + (size_t)3 * N * 64;
  float* den   = ws + (size_t)4 * N * 64;
  int*      cursor = (int*)(ws + (size_t)5 * N * 64);
  uint32_t* sorted = (uint32_t*)(cursor + N);

  hipMemsetAsync(num, 0, (size_t)2 * N * 64 * sizeof(float), stream);
  hipMemsetAsync(cursor, 0, (size_t)N * sizeof(int), stream);

  hist_kernel<<<(E + 255) / 256, 256, 0, stream>>>(eidx, cursor, E);
  scan_kernel<<<1, 1024, 0, stream>>>(cursor, N);
  scatter_kernel<<<(E + 255) / 256, 256, 0, stream>>>(eidx, cursor, sorted, E);

  node_in_mfma<<<784, 256, 0, stream>>>(x, W_in, b_in, W_lin, W_src, W_dst,
                                        v, a_src, a_dst, N);
  edge_mfma_kernel<<<512, 512, 0, stream>>>(pos, v, a_src, a_dst,
                                            pW1, pb1, pW2, pb2, aW1, ab1, aW2, ab2,
                                            sorted, num, den, E);
  node_out_mfma<<<392, 512, 0, stream>>>(num, den, W_out, b_out, (float*)d_out, N);
}

// Round 6
// 230.598 us; speedup vs baseline: 6.2494x; 1.3321x over previous
//
#include <hip/hip_runtime.h>
#include <hip/hip_bf16.h>

// Round 6: (1) hardware v_cvt_pk_bf16_f32 for ALL bf16 packing (edge kernel was
// VALU-bound on software round-to-nearest-even), (2) weight fragments prepacked
// once to workspace -> consumers stage with coalesced uint4 copies, (3) parallel
// 3-phase scan replaces single-block serial scan, (4) vectorized hist.

using bf16x8 = __attribute__((ext_vector_type(8))) short;
using f32x4  = __attribute__((ext_vector_type(4))) float;

__device__ __forceinline__ uint32_t cvtpk(float a, float b) {
  uint32_t d;
  asm("v_cvt_pk_bf16_f32 %0, %1, %2" : "=v"(d) : "v"(a), "v"(b));
  return d;   // lo16 = bf16(a), hi16 = bf16(b), RNE
}
__device__ __forceinline__ float bf2f(short s) {
  union { uint32_t u; float f; } v; v.u = ((uint32_t)(uint16_t)s) << 16;
  return v.f;
}
__device__ __forceinline__ bf16x8 mk8(uint32_t a, uint32_t b, uint32_t c, uint32_t d) {
  union { uint4 q; bf16x8 v; } u;
  u.q.x = a; u.q.y = b; u.q.z = c; u.q.w = d;
  return u.v;
}
__device__ __forceinline__ f32x4 mfma16(bf16x8 a, bf16x8 b, f32x4 c) {
  return __builtin_amdgcn_mfma_f32_16x16x32_bf16(a, b, c, 0, 0, 0);
}
#define LGKM0 asm volatile("s_waitcnt lgkmcnt(0)" ::: "memory")

// ================= weight fragment prepack =================
// frag[0..1535]   : pW2, aW1, aW2      (edge)
// frag[1536..3583]: W_in, W_lin, W_src, W_dst (node_in)
// frag[3584..4095]: W_out              (node_out)
__global__ __launch_bounds__(256) void prepack_kernel(
    const float* __restrict__ pW2, const float* __restrict__ aW1, const float* __restrict__ aW2,
    const float* __restrict__ W_in, const float* __restrict__ W_lin,
    const float* __restrict__ W_src, const float* __restrict__ W_dst,
    const float* __restrict__ W_out, uint4* __restrict__ frag) {
  const int idx = blockIdx.x * 256 + threadIdx.x;
  if (idx >= 64 * 64) return;
  const int f = idx >> 6, lane = idx & 63;
  const float* W; int fl;
  if      (f <  8) { W = pW2;   fl = f;      }
  else if (f < 16) { W = aW1;   fl = f -  8; }
  else if (f < 24) { W = aW2;   fl = f - 16; }
  else if (f < 32) { W = W_in;  fl = f - 24; }
  else if (f < 40) { W = W_lin; fl = f - 32; }
  else if (f < 48) { W = W_src; fl = f - 40; }
  else if (f < 56) { W = W_dst; fl = f - 48; }
  else             { W = W_out; fl = f - 56; }
  const int half = (fl >> 2) & 1, t = fl & 3;
  const int lo = lane & 15, hi = lane >> 4;
  const int c = t * 16 + lo;
  uint4 q;
  {
    const int k = 32 * half + hi * 8;
    q.x = cvtpk(W[(k + 0) * 64 + c], W[(k + 1) * 64 + c]);
    q.y = cvtpk(W[(k + 2) * 64 + c], W[(k + 3) * 64 + c]);
    q.z = cvtpk(W[(k + 4) * 64 + c], W[(k + 5) * 64 + c]);
    q.w = cvtpk(W[(k + 6) * 64 + c], W[(k + 7) * 64 + c]);
  }
  frag[idx] = q;
}

// ================= sort kernels =================
__global__ __launch_bounds__(256) void hist_kernel(
    const int* __restrict__ eidx, int* __restrict__ cursor, int E) {
  const int i = blockIdx.x * 256 + threadIdx.x;
  const int base = i * 4;
  if (base + 3 < E) {
    const int4 d = *(const int4*)(eidx + E + base);
    atomicAdd(&cursor[d.x], 1);
    atomicAdd(&cursor[d.y], 1);
    atomicAdd(&cursor[d.z], 1);
    atomicAdd(&cursor[d.w], 1);
  } else {
    for (int j = base; j < E; ++j) atomicAdd(&cursor[eidx[E + j]], 1);
  }
}

#define SCAN_CH 1024
__global__ __launch_bounds__(256) void scan_blocksum(
    const int* __restrict__ cursor, int* __restrict__ bsum, int N) {
  __shared__ int red[4];
  const int base = blockIdx.x * SCAN_CH + threadIdx.x * 4;
  int s = 0;
#pragma unroll
  for (int j = 0; j < 4; ++j) { const int i = base + j; if (i < N) s += cursor[i]; }
  for (int off = 1; off < 64; off <<= 1) s += __shfl_xor(s, off);
  if ((threadIdx.x & 63) == 0) red[threadIdx.x >> 6] = s;
  __syncthreads();
  if (threadIdx.x == 0) bsum[blockIdx.x] = red[0] + red[1] + red[2] + red[3];
}

__global__ __launch_bounds__(64) void scan_bsum_prefix(int* __restrict__ bsum, int nb) {
  const int t = threadIdx.x;
  const int orig = (t < nb) ? bsum[t] : 0;
  int v = orig;
  for (int off = 1; off < 64; off <<= 1) {
    const int u = __shfl_up(v, off);
    if (t >= off) v += u;
  }
  if (t < nb) bsum[t] = v - orig;   // exclusive
}

__global__ __launch_bounds__(256) void scan_final(
    int* __restrict__ cursor, const int* __restrict__ bsum, int N) {
  __shared__ int woff[4];
  const int base = blockIdx.x * SCAN_CH + threadIdx.x * 4;
  int x[4]; int s = 0;
#pragma unroll
  for (int j = 0; j < 4; ++j) { const int i = base + j; x[j] = (i < N) ? cursor[i] : 0; s += x[j]; }
  int v = s;
  const int lane = threadIdx.x & 63, wid = threadIdx.x >> 6;
  for (int off = 1; off < 64; off <<= 1) {
    const int u = __shfl_up(v, off);
    if (lane >= off) v += u;
  }
  if (lane == 63) woff[wid] = v;
  __syncthreads();
  int waveoff = 0;
  for (int k = 0; k < 4; ++k) waveoff += (k < wid) ? woff[k] : 0;
  int ex = v - s + waveoff + bsum[blockIdx.x];
#pragma unroll
  for (int j = 0; j < 4; ++j) {
    const int i = base + j;
    if (i < N) { cursor[i] = ex; ex += x[j]; }
  }
}

__global__ __launch_bounds__(256) void scatter_kernel(
    const int* __restrict__ eidx, int* __restrict__ cursor,
    uint32_t* __restrict__ sorted, int E) {
  const int e = blockIdx.x * 256 + threadIdx.x;
  if (e < E) {
    const int s = eidx[e];
    const int d = eidx[E + e];
    const int slot = atomicAdd(&cursor[d], 1);
    sorted[slot] = ((uint32_t)d << 16) | (uint32_t)s;
  }
}

// ================= edge kernel =================
__global__ __launch_bounds__(512, 4) void edge_mfma_kernel(
    const float* __restrict__ pos,
    const float* __restrict__ v, const float* __restrict__ a_src, const float* __restrict__ a_dst,
    const float* __restrict__ pW1, const float* __restrict__ pb1,
    const float* __restrict__ pb2, const float* __restrict__ ab1, const float* __restrict__ ab2,
    const uint4* __restrict__ frag,
    const uint32_t* __restrict__ sorted,
    float* __restrict__ num, float* __restrict__ den, int E) {
  __shared__ uint32_t sWfrag[24][64][4];     // 24 KB
  __shared__ float    sSmall[448];
  __shared__ float    sXp[8][16 * 68];       // 34.8 KB
  __shared__ int      sDst[8][16];

  const int tid = threadIdx.x;
  for (int i = tid; i < 448; i += 512) {
    float val;
    if      (i < 192) val = pW1[i];
    else if (i < 256) val = pb1[i - 192];
    else if (i < 320) val = pb2[i - 256];
    else if (i < 384) val = ab1[i - 320];
    else              val = ab2[i - 384];
    sSmall[i] = val;
  }
  {
    uint4* sW4 = (uint4*)sWfrag;
    for (int i = tid; i < 24 * 64; i += 512) sW4[i] = frag[i];
  }
  __syncthreads();

  const int w  = tid >> 6, l = tid & 63;
  const int lo = l & 15,  hi = l >> 4;
  float*   xb     = &sXp[w][0];
  uint8_t* trbase = (uint8_t*)xb;
  const uint32_t swz = (uint32_t)((lo & 7) << 4);
  const int ho = hi * 8;

#define WF(m, half, t) (*(const bf16x8*)&sWfrag[(m) * 8 + (half) * 4 + (t)][l][0])

  const int ntiles = (E + 15) >> 4;
  const int stride = gridDim.x * 8;

  int cs = 0, cd = 0; float c0 = 0.f, c1 = 0.f, c2 = 0.f;
  {
    const int t0 = blockIdx.x * 8 + w;
    if (t0 < ntiles) {
      const int ee = t0 * 16 + lo;
      const int ec = ee < E ? ee : (E - 1);
      const uint32_t se = sorted[ec];
      cs = (int)(se & 0xFFFFu); cd = (int)(se >> 16);
      c0 = pos[cd * 3 + 0] - pos[cs * 3 + 0];
      c1 = pos[cd * 3 + 1] - pos[cs * 3 + 1];
      c2 = pos[cd * 3 + 2] - pos[cs * 3 + 2];
    }
  }

  for (int tile = blockIdx.x * 8 + w; tile < ntiles; tile += stride) {
    const int src = cs, dst = cd;
    const float d0 = c0, d1 = c1, d2 = c2;
    const size_t db = (size_t)dst * 64, sb = (size_t)src * 64;

    const f32x4 Ad00 = *(const f32x4*)&a_dst[db + ho];
    const f32x4 Ad01 = *(const f32x4*)&a_dst[db + ho + 4];
    const f32x4 Ad10 = *(const f32x4*)&a_dst[db + 32 + ho];
    const f32x4 Ad11 = *(const f32x4*)&a_dst[db + 32 + ho + 4];
    const f32x4 As00 = *(const f32x4*)&a_src[sb + ho];
    const f32x4 As01 = *(const f32x4*)&a_src[sb + ho + 4];
    const f32x4 As10 = *(const f32x4*)&a_src[sb + 32 + ho];
    const f32x4 As11 = *(const f32x4*)&a_src[sb + 32 + ho + 4];

    const int nt = tile + stride;
    if (nt < ntiles) {
      const int ee = nt * 16 + lo;
      const int ec = ee < E ? ee : (E - 1);
      const uint32_t se = sorted[ec];
      cs = (int)(se & 0xFFFFu); cd = (int)(se >> 16);
      c0 = pos[cd * 3 + 0] - pos[cs * 3 + 0];
      c1 = pos[cd * 3 + 1] - pos[cs * 3 + 1];
      c2 = pos[cd * 3 + 2] - pos[cs * 3 + 2];
    }

    if (hi == 0) sDst[w][lo] = dst;

    // pos layer 1 (3->64) in B-frag layout, hardware pack
    bf16x8 hf[2];
#pragma unroll
    for (int half = 0; half < 2; ++half) {
      float t8[8];
#pragma unroll
      for (int i = 0; i < 8; ++i) {
        const int k = 32 * half + hi * 8 + i;
        t8[i] = fmaxf(sSmall[192 + k] + d0 * sSmall[k] + d1 * sSmall[64 + k] + d2 * sSmall[128 + k], 0.f);
      }
      hf[half] = mk8(cvtpk(t8[0], t8[1]), cvtpk(t8[2], t8[3]),
                     cvtpk(t8[4], t8[5]), cvtpk(t8[6], t8[7]));
    }
    // pos layer 2
    f32x4 dl[4];
#pragma unroll
    for (int t = 0; t < 4; ++t) {
      f32x4 acc = *(const f32x4*)&sSmall[256 + t * 16 + hi * 4];
      acc = mfma16(WF(0, 0, t), hf[0], acc);
      acc = mfma16(WF(0, 1, t), hf[1], acc);
#pragma unroll
      for (int r = 0; r < 4; ++r) dl[t][r] = fmaxf(acc[r], 0.f);
    }
    // transpose delta
    LGKM0;
#pragma unroll
    for (int t = 0; t < 4; ++t) {
      uint2 p; p.x = cvtpk(dl[t][0], dl[t][1]); p.y = cvtpk(dl[t][2], dl[t][3]);
      *(uint2*)(trbase + lo * 128 + (((uint32_t)(t * 32 + hi * 8)) ^ swz)) = p;
    }
    LGKM0;
    const bf16x8 dfr0 = *(const bf16x8*)(trbase + lo * 128 + (((uint32_t)(hi * 16)) ^ swz));
    const bf16x8 dfr1 = *(const bf16x8*)(trbase + lo * 128 + (((uint32_t)(64 + hi * 16)) ^ swz));

    bf16x8 tf[2];
    {
      float t8[8];
#pragma unroll
      for (int i = 0; i < 8; ++i)
        t8[i] = ((i < 4) ? Ad00[i] : Ad01[i - 4]) - ((i < 4) ? As00[i] : As01[i - 4]) + bf2f(dfr0[i]);
      tf[0] = mk8(cvtpk(t8[0], t8[1]), cvtpk(t8[2], t8[3]),
                  cvtpk(t8[4], t8[5]), cvtpk(t8[6], t8[7]));
#pragma unroll
      for (int i = 0; i < 8; ++i)
        t8[i] = ((i < 4) ? Ad10[i] : Ad11[i - 4]) - ((i < 4) ? As10[i] : As11[i - 4]) + bf2f(dfr1[i]);
      tf[1] = mk8(cvtpk(t8[0], t8[1]), cvtpk(t8[2], t8[3]),
                  cvtpk(t8[4], t8[5]), cvtpk(t8[6], t8[7]));
    }

    f32x4 V[4];
#pragma unroll
    for (int t = 0; t < 4; ++t) V[t] = *(const f32x4*)&v[sb + t * 16 + hi * 4];

    // attn layer 1
    f32x4 ga[4];
#pragma unroll
    for (int t = 0; t < 4; ++t) {
      f32x4 acc = *(const f32x4*)&sSmall[320 + t * 16 + hi * 4];
      acc = mfma16(WF(1, 0, t), tf[0], acc);
      acc = mfma16(WF(1, 1, t), tf[1], acc);
#pragma unroll
      for (int r = 0; r < 4; ++r) ga[t][r] = fmaxf(acc[r], 0.f);
    }
#pragma unroll
    for (int t = 0; t < 4; ++t) {
      uint2 p; p.x = cvtpk(ga[t][0], ga[t][1]); p.y = cvtpk(ga[t][2], ga[t][3]);
      *(uint2*)(trbase + 2048 + lo * 128 + (((uint32_t)(t * 32 + hi * 8)) ^ swz)) = p;
    }
    LGKM0;
    const bf16x8 gf0 = *(const bf16x8*)(trbase + 2048 + lo * 128 + (((uint32_t)(hi * 16)) ^ swz));
    const bf16x8 gf1 = *(const bf16x8*)(trbase + 2048 + lo * 128 + (((uint32_t)(64 + hi * 16)) ^ swz));

    // attn layer 2 -> ex
    f32x4 exv[4];
#pragma unroll
    for (int t = 0; t < 4; ++t) {
      f32x4 acc = *(const f32x4*)&sSmall[384 + t * 16 + hi * 4];
      acc = mfma16(WF(2, 0, t), gf0, acc);
      acc = mfma16(WF(2, 1, t), gf1, acc);
      f32x4 nv;
#pragma unroll
      for (int r = 0; r < 4; ++r) {
        const float ex = __expf(fmaxf(acc[r], 0.f));
        exv[t][r] = ex;
        nv[r] = ex * (V[t][r] + dl[t][r]);
      }
      *(f32x4*)&xb[lo * 68 + t * 16 + hi * 4] = nv;
    }
    LGKM0;
    const int tbase = tile * 16;
    {
      int run_d = __builtin_amdgcn_readfirstlane(sDst[w][0]);
      float acc = 0.f;
#pragma unroll
      for (int ee = 0; ee < 16; ++ee) {
        if (tbase + ee < E) {
          const int de = __builtin_amdgcn_readfirstlane(sDst[w][ee]);
          const float nv = xb[ee * 68 + l];
          if (de != run_d) {
            atomicAdd(&num[(size_t)run_d * 64 + l], acc);
            run_d = de; acc = 0.f;
          }
          acc += nv;
        }
      }
      atomicAdd(&num[(size_t)run_d * 64 + l], acc);
    }
#pragma unroll
    for (int t = 0; t < 4; ++t)
      *(f32x4*)&xb[lo * 68 + t * 16 + hi * 4] = exv[t];
    LGKM0;
    {
      int run_d = __builtin_amdgcn_readfirstlane(sDst[w][0]);
      float acc = 0.f;
#pragma unroll
      for (int ee = 0; ee < 16; ++ee) {
        if (tbase + ee < E) {
          const int de = __builtin_amdgcn_readfirstlane(sDst[w][ee]);
          const float dv = xb[ee * 68 + l];
          if (de != run_d) {
            atomicAdd(&den[(size_t)run_d * 64 + l], acc);
            run_d = de; acc = 0.f;
          }
          acc += dv;
        }
      }
      atomicAdd(&den[(size_t)run_d * 64 + l], acc);
    }
  }
#undef WF
}

// ================= node_in (MFMA) =================
__global__ __launch_bounds__(256, 4) void node_in_mfma(
    const float* __restrict__ x, const float* __restrict__ b_in,
    const uint4* __restrict__ frag,
    float* __restrict__ v, float* __restrict__ a_src, float* __restrict__ a_dst, int N) {
  __shared__ uint32_t sWfrag[32][64][4];
  __shared__ float    sBias[64];
  __shared__ float    sXp[4][16 * 68];

  const int tid = threadIdx.x;
  {
    uint4* sW4 = (uint4*)sWfrag;
    const uint4* src = frag + 24 * 64;
    for (int i = tid; i < 32 * 64; i += 256) sW4[i] = src[i];
  }
  if (tid < 64) sBias[tid] = b_in[tid];
  __syncthreads();

  const int w  = tid >> 6, l = tid & 63;
  const int lo = l & 15,  hi = l >> 4;
  float*   xb     = &sXp[w][0];
  uint8_t* trbase = (uint8_t*)xb;
  const uint32_t swz = (uint32_t)((lo & 7) << 4);

#define WF(m, half, t) (*(const bf16x8*)&sWfrag[(m) * 8 + (half) * 4 + (t)][l][0])

  const int ntiles = (N + 15) >> 4;
  for (int tile = blockIdx.x * 4 + w; tile < ntiles; tile += gridDim.x * 4) {
    const int row = tile * 16 + lo;
    const int rowc = row < N ? row : (N - 1);
    bf16x8 xf[2];
#pragma unroll
    for (int half = 0; half < 2; ++half) {
      const int base = 32 * half + hi * 8;
      const f32x4 X0 = *(const f32x4*)&x[(size_t)rowc * 64 + base];
      const f32x4 X1 = *(const f32x4*)&x[(size_t)rowc * 64 + base + 4];
      xf[half] = mk8(cvtpk(X0[0], X0[1]), cvtpk(X0[2], X0[3]),
                     cvtpk(X1[0], X1[1]), cvtpk(X1[2], X1[3]));
    }
    f32x4 x1[4];
#pragma unroll
    for (int t = 0; t < 4; ++t) {
      f32x4 acc = *(const f32x4*)&sBias[t * 16 + hi * 4];
      acc = mfma16(WF(0, 0, t), xf[0], acc);
      acc = mfma16(WF(0, 1, t), xf[1], acc);
#pragma unroll
      for (int r = 0; r < 4; ++r) x1[t][r] = fmaxf(acc[r], 0.f);
    }
    LGKM0;
#pragma unroll
    for (int t = 0; t < 4; ++t) {
      uint2 p; p.x = cvtpk(x1[t][0], x1[t][1]); p.y = cvtpk(x1[t][2], x1[t][3]);
      *(uint2*)(trbase + lo * 128 + (((uint32_t)(t * 32 + hi * 8)) ^ swz)) = p;
    }
    LGKM0;
    const bf16x8 x1f0 = *(const bf16x8*)(trbase + lo * 128 + (((uint32_t)(hi * 16)) ^ swz));
    const bf16x8 x1f1 = *(const bf16x8*)(trbase + lo * 128 + (((uint32_t)(64 + hi * 16)) ^ swz));

#pragma unroll
    for (int m = 1; m <= 3; ++m) {
      f32x4 res[4];
#pragma unroll
      for (int t = 0; t < 4; ++t) {
        f32x4 acc = {0.f, 0.f, 0.f, 0.f};
        acc = mfma16(WF(m, 0, t), x1f0, acc);
        acc = mfma16(WF(m, 1, t), x1f1, acc);
        res[t] = acc;
      }
#pragma unroll
      for (int t = 0; t < 4; ++t)
        *(f32x4*)&xb[lo * 68 + t * 16 + hi * 4] = res[t];
      LGKM0;
      float* out = (m == 1) ? v : (m == 2) ? a_src : a_dst;
#pragma unroll
      for (int ee = 0; ee < 16; ++ee) {
        const int r2 = tile * 16 + ee;
        if (r2 < N) out[(size_t)r2 * 64 + l] = xb[ee * 68 + l];
      }
      LGKM0;
    }
  }
#undef WF
}

// ================= node_out (MFMA) =================
__global__ __launch_bounds__(512, 4) void node_out_mfma(
    const float* __restrict__ num, const float* __restrict__ den,
    const uint4* __restrict__ frag, const float* __restrict__ b_out,
    float* __restrict__ out, int N) {
  __shared__ uint32_t sWfrag[8][64][4];
  __shared__ float    sBias[64];
  __shared__ float    sXp[8][16 * 68];

  const int tid = threadIdx.x;
  {
    uint4* sW4 = (uint4*)sWfrag;
    const uint4* src = frag + 56 * 64;
    for (int i = tid; i < 8 * 64; i += 512) sW4[i] = src[i];
  }
  if (tid < 64) sBias[tid] = b_out[tid];
  __syncthreads();

  const int w  = tid >> 6, l = tid & 63;
  const int lo = l & 15,  hi = l >> 4;
  float* xb = &sXp[w][0];

#define WFo(half, t) (*(const bf16x8*)&sWfrag[(half) * 4 + (t)][l][0])

  const int ntiles = (N + 15) >> 4;
  for (int tile = blockIdx.x * 8 + w; tile < ntiles; tile += gridDim.x * 8) {
    const int row = tile * 16 + lo;
    const int rowc = row < N ? row : (N - 1);
    bf16x8 sf[2];
#pragma unroll
    for (int half = 0; half < 2; ++half) {
      const int base = 32 * half + hi * 8;
      const f32x4 N0 = *(const f32x4*)&num[(size_t)rowc * 64 + base];
      const f32x4 N1 = *(const f32x4*)&num[(size_t)rowc * 64 + base + 4];
      const f32x4 D0 = *(const f32x4*)&den[(size_t)rowc * 64 + base];
      const f32x4 D1 = *(const f32x4*)&den[(size_t)rowc * 64 + base + 4];
      float t8[8];
#pragma unroll
      for (int i = 0; i < 8; ++i) {
        const float nn = (i < 4) ? N0[i] : N1[i - 4];
        const float dd = (i < 4) ? D0[i] : D1[i - 4];
        t8[i] = nn / (dd + 1e-16f);
      }
      sf[half] = mk8(cvtpk(t8[0], t8[1]), cvtpk(t8[2], t8[3]),
                     cvtpk(t8[4], t8[5]), cvtpk(t8[6], t8[7]));
    }
    f32x4 res[4];
#pragma unroll
    for (int t = 0; t < 4; ++t) {
      f32x4 acc = *(const f32x4*)&sBias[t * 16 + hi * 4];
      acc = mfma16(WFo(0, t), sf[0], acc);
      acc = mfma16(WFo(1, t), sf[1], acc);
#pragma unroll
      for (int r = 0; r < 4; ++r) res[t][r] = fmaxf(acc[r], 0.f);
    }
    LGKM0;
#pragma unroll
    for (int t = 0; t < 4; ++t)
      *(f32x4*)&xb[lo * 68 + t * 16 + hi * 4] = res[t];
    LGKM0;
#pragma unroll
    for (int ee = 0; ee < 16; ++ee) {
      const int r2 = tile * 16 + ee;
      if (r2 < N) out[(size_t)r2 * 64 + l] = xb[ee * 68 + l];
    }
  }
#undef WFo
}

extern "C" void kernel_launch(void* const* d_in, const int* in_sizes, int n_in,
                              void* d_out, int out_size, void* d_ws, size_t ws_size,
                              hipStream_t stream) {
  const float* x     = (const float*)d_in[0];
  const float* pos   = (const float*)d_in[1];
  const float* W_in  = (const float*)d_in[2];
  const float* b_in  = (const float*)d_in[3];
  const float* W_lin = (const float*)d_in[4];
  const float* W_src = (const float*)d_in[5];
  const float* W_dst = (const float*)d_in[6];
  const float* pW1   = (const float*)d_in[7];
  const float* pb1   = (const float*)d_in[8];
  const float* pW2   = (const float*)d_in[9];
  const float* pb2   = (const float*)d_in[10];
  const float* aW1   = (const float*)d_in[11];
  const float* ab1   = (const float*)d_in[12];
  const float* aW2   = (const float*)d_in[13];
  const float* ab2   = (const float*)d_in[14];
  const float* W_out = (const float*)d_in[15];
  const float* b_out = (const float*)d_in[16];
  const int*   eidx  = (const int*)d_in[17];

  const int N = in_sizes[0] / 64;
  const int E = in_sizes[17] / 2;

  float* ws    = (float*)d_ws;
  float* v     = ws;
  float* a_src = ws + (size_t)1 * N * 64;
  float* a_dst = ws + (size_t)2 * N * 64;
  float* num   = ws + (size_t)3 * N * 64;
  float* den   = ws + (size_t)4 * N * 64;
  int*      cursor = (int*)(ws + (size_t)5 * N * 64);
  uint32_t* sorted = (uint32_t*)(cursor + N);
  uint4*    frag   = (uint4*)(sorted + E);
  int*      bsum   = (int*)(frag + 64 * 64);

  hipMemsetAsync(num, 0, (size_t)2 * N * 64 * sizeof(float), stream);
  hipMemsetAsync(cursor, 0, (size_t)N * sizeof(int), stream);

  prepack_kernel<<<16, 256, 0, stream>>>(pW2, aW1, aW2, W_in, W_lin, W_src, W_dst,
                                         W_out, frag);
  hist_kernel<<<(E / 4 + 255) / 256 + 1, 256, 0, stream>>>(eidx, cursor, E);
  const int nb = (N + SCAN_CH - 1) / SCAN_CH;
  scan_blocksum<<<nb, 256, 0, stream>>>(cursor, bsum, N);
  scan_bsum_prefix<<<1, 64, 0, stream>>>(bsum, nb);
  scan_final<<<nb, 256, 0, stream>>>(cursor, bsum, N);
  scatter_kernel<<<(E + 255) / 256, 256, 0, stream>>>(eidx, cursor, sorted, E);

  node_in_mfma<<<784, 256, 0, stream>>>(x, b_in, frag, v, a_src, a_dst, N);
  edge_mfma_kernel<<<512, 512, 0, stream>>>(pos, v, a_src, a_dst,
                                            pW1, pb1, pb2, ab1, ab2,
                                            frag, sorted, num, den, E);
  node_out_mfma<<<392, 512, 0, stream>>>(num, den, frag + 0, b_out, (float*)d_out, N);
}

// Round 8
// 208.516 us; speedup vs baseline: 6.9112x; 1.1059x over previous
//
#include <hip/hip_runtime.h>
#include <hip/hip_bf16.h>

// Round 8 = Round 7 with the frag race fixed:
//   fused_prep = {prepack(16 blocks) + hist(HB) + node_in}, but node_in blocks
//   build their own LDS weight fragments from raw W (no intra-dispatch dependency
//   on frag). frag is consumed only by later dispatches (edge, node_out).
//   Scan reverted to the proven 3-phase version (round 6).

using bf16x8 = __attribute__((ext_vector_type(8))) short;
using f32x4  = __attribute__((ext_vector_type(4))) float;
using u16x8  = __attribute__((ext_vector_type(8))) unsigned short;
using u16x4  = __attribute__((ext_vector_type(4))) unsigned short;

__device__ __forceinline__ uint32_t cvtpk(float a, float b) {
  uint32_t d;
  asm("v_cvt_pk_bf16_f32 %0, %1, %2" : "=v"(d) : "v"(a), "v"(b));
  return d;
}
__device__ __forceinline__ float bf2f(unsigned short s) {
  union { uint32_t u; float f; } v; v.u = ((uint32_t)s) << 16;
  return v.f;
}
__device__ __forceinline__ float bf2fs(short s) { return bf2f((unsigned short)s); }
__device__ __forceinline__ bf16x8 mk8(uint32_t a, uint32_t b, uint32_t c, uint32_t d) {
  union { uint4 q; bf16x8 v; } u;
  u.q.x = a; u.q.y = b; u.q.z = c; u.q.w = d;
  return u.v;
}
__device__ __forceinline__ f32x4 mfma16(bf16x8 a, bf16x8 b, f32x4 c) {
  return __builtin_amdgcn_mfma_f32_16x16x32_bf16(a, b, c, 0, 0, 0);
}
#define LGKM0 asm volatile("s_waitcnt lgkmcnt(0)" ::: "memory")

// ================= fused prep: prepack + hist + node_in =================
__global__ __launch_bounds__(256, 3) void fused_prep_kernel(
    const float* __restrict__ pW2, const float* __restrict__ aW1, const float* __restrict__ aW2,
    const float* __restrict__ W_in, const float* __restrict__ W_lin,
    const float* __restrict__ W_src, const float* __restrict__ W_dst,
    const float* __restrict__ W_out, uint4* __restrict__ frag,
    const int* __restrict__ eidx, int* __restrict__ cursor, int E,
    const float* __restrict__ x, const float* __restrict__ b_in,
    unsigned short* __restrict__ vbf, unsigned short* __restrict__ abf,
    float* __restrict__ adst, int N, int HB) {
  __shared__ uint32_t sWfrag[32][64][4];
  __shared__ float    sBias[64];
  __shared__ float    sXp[4][16 * 68];

  const int tid = threadIdx.x;

  // ---------- role: prepack (frag consumed ONLY by later dispatches) ----------
  if (blockIdx.x < 16) {
    const int idx = blockIdx.x * 256 + tid;
    const int f = idx >> 6, lane = idx & 63;
    const float* W; int fl;
    if      (f <  8) { W = pW2;   fl = f;      }
    else if (f < 16) { W = aW1;   fl = f -  8; }
    else if (f < 24) { W = aW2;   fl = f - 16; }
    else if (f < 32) { W = W_in;  fl = f - 24; }
    else if (f < 40) { W = W_lin; fl = f - 32; }
    else if (f < 48) { W = W_src; fl = f - 40; }
    else if (f < 56) { W = W_dst; fl = f - 48; }
    else             { W = W_out; fl = f - 56; }
    const int half = (fl >> 2) & 1, t = fl & 3;
    const int lo = lane & 15, hi = lane >> 4;
    const int c = t * 16 + lo;
    const int k = 32 * half + hi * 8;
    uint4 q;
    q.x = cvtpk(W[(k + 0) * 64 + c], W[(k + 1) * 64 + c]);
    q.y = cvtpk(W[(k + 2) * 64 + c], W[(k + 3) * 64 + c]);
    q.z = cvtpk(W[(k + 4) * 64 + c], W[(k + 5) * 64 + c]);
    q.w = cvtpk(W[(k + 6) * 64 + c], W[(k + 7) * 64 + c]);
    frag[idx] = q;
    return;
  }
  int bid = blockIdx.x - 16;

  // ---------- role: hist ----------
  if (bid < HB) {
    const int base = (bid * 256 + tid) * 4;
    if (base + 3 < E) {
      const int4 d = *(const int4*)(eidx + E + base);
      atomicAdd(&cursor[d.x], 1);
      atomicAdd(&cursor[d.y], 1);
      atomicAdd(&cursor[d.z], 1);
      atomicAdd(&cursor[d.w], 1);
    } else {
      for (int j = base; j < E; ++j) atomicAdd(&cursor[eidx[E + j]], 1);
    }
    return;
  }
  bid -= HB;
  const int nbn = gridDim.x - 16 - HB;

  // ---------- role: node_in (builds its OWN frags from raw weights) ----------
  for (int idx = tid; idx < 32 * 64; idx += 256) {
    const int f = idx >> 6, lane = idx & 63;
    const int m = f >> 3, half = (f >> 2) & 1, t = f & 3;
    const float* W = (m == 0) ? W_in : (m == 1) ? W_lin : (m == 2) ? W_src : W_dst;
    const int lo = lane & 15, hi = lane >> 4;
    const int c = t * 16 + lo;
    const int k = 32 * half + hi * 8;
    uint4 q;
    q.x = cvtpk(W[(k + 0) * 64 + c], W[(k + 1) * 64 + c]);
    q.y = cvtpk(W[(k + 2) * 64 + c], W[(k + 3) * 64 + c]);
    q.z = cvtpk(W[(k + 4) * 64 + c], W[(k + 5) * 64 + c]);
    q.w = cvtpk(W[(k + 6) * 64 + c], W[(k + 7) * 64 + c]);
    *(uint4*)&sWfrag[f][lane][0] = q;
  }
  if (tid < 64) sBias[tid] = b_in[tid];
  __syncthreads();

  const int w  = tid >> 6, l = tid & 63;
  const int lo = l & 15,  hi = l >> 4;
  float*   xb     = &sXp[w][0];
  uint8_t* trbase = (uint8_t*)xb;
  const uint32_t swz = (uint32_t)((lo & 7) << 4);
  const int rr = l >> 5, cc = l & 31;

#define WF(m, half, t) (*(const bf16x8*)&sWfrag[(m) * 8 + (half) * 4 + (t)][l][0])

  const int ntiles = (N + 15) >> 4;
  for (int tile = bid * 4 + w; tile < ntiles; tile += nbn * 4) {
    const int row = tile * 16 + lo;
    const int rowc = row < N ? row : (N - 1);
    bf16x8 xf[2];
#pragma unroll
    for (int half = 0; half < 2; ++half) {
      const int base = 32 * half + hi * 8;
      const f32x4 X0 = *(const f32x4*)&x[(size_t)rowc * 64 + base];
      const f32x4 X1 = *(const f32x4*)&x[(size_t)rowc * 64 + base + 4];
      xf[half] = mk8(cvtpk(X0[0], X0[1]), cvtpk(X0[2], X0[3]),
                     cvtpk(X1[0], X1[1]), cvtpk(X1[2], X1[3]));
    }
    f32x4 x1[4];
#pragma unroll
    for (int t = 0; t < 4; ++t) {
      f32x4 acc = *(const f32x4*)&sBias[t * 16 + hi * 4];
      acc = mfma16(WF(0, 0, t), xf[0], acc);
      acc = mfma16(WF(0, 1, t), xf[1], acc);
#pragma unroll
      for (int r = 0; r < 4; ++r) x1[t][r] = fmaxf(acc[r], 0.f);
    }
    LGKM0;
#pragma unroll
    for (int t = 0; t < 4; ++t) {
      uint2 p; p.x = cvtpk(x1[t][0], x1[t][1]); p.y = cvtpk(x1[t][2], x1[t][3]);
      *(uint2*)(trbase + lo * 128 + (((uint32_t)(t * 32 + hi * 8)) ^ swz)) = p;
    }
    LGKM0;
    const bf16x8 x1f0 = *(const bf16x8*)(trbase + lo * 128 + (((uint32_t)(hi * 16)) ^ swz));
    const bf16x8 x1f1 = *(const bf16x8*)(trbase + lo * 128 + (((uint32_t)(64 + hi * 16)) ^ swz));

#pragma unroll
    for (int m = 1; m <= 3; ++m) {
      f32x4 res[4];
#pragma unroll
      for (int t = 0; t < 4; ++t) {
        f32x4 acc = {0.f, 0.f, 0.f, 0.f};
        acc = mfma16(WF(m, 0, t), x1f0, acc);
        acc = mfma16(WF(m, 1, t), x1f1, acc);
        res[t] = acc;
      }
#pragma unroll
      for (int t = 0; t < 4; ++t)
        *(f32x4*)&xb[lo * 68 + t * 16 + hi * 4] = res[t];
      LGKM0;
      if (m == 3) {
#pragma unroll
        for (int ee = 0; ee < 16; ++ee) {
          const int r2 = tile * 16 + ee;
          if (r2 < N) adst[(size_t)r2 * 64 + l] = xb[ee * 68 + l];
        }
      } else {
        unsigned short* outp = (m == 1) ? vbf : abf;
#pragma unroll
        for (int ee2 = 0; ee2 < 16; ee2 += 2) {
          const int er = ee2 + rr;
          const int r2 = tile * 16 + er;
          const uint32_t pk = cvtpk(xb[er * 68 + 2 * cc], xb[er * 68 + 2 * cc + 1]);
          if (r2 < N) *(uint32_t*)&outp[(size_t)r2 * 64 + 2 * cc] = pk;
        }
      }
      LGKM0;
    }
  }
#undef WF
}

// ================= 3-phase scan (proven, round 6) =================
#define SCAN_CH 1024
__global__ __launch_bounds__(256) void scan_blocksum(
    const int* __restrict__ cursor, int* __restrict__ bsum, int N) {
  __shared__ int red[4];
  const int base = blockIdx.x * SCAN_CH + threadIdx.x * 4;
  int s = 0;
#pragma unroll
  for (int j = 0; j < 4; ++j) { const int i = base + j; if (i < N) s += cursor[i]; }
  for (int off = 1; off < 64; off <<= 1) s += __shfl_xor(s, off);
  if ((threadIdx.x & 63) == 0) red[threadIdx.x >> 6] = s;
  __syncthreads();
  if (threadIdx.x == 0) bsum[blockIdx.x] = red[0] + red[1] + red[2] + red[3];
}

__global__ __launch_bounds__(64) void scan_bsum_prefix(int* __restrict__ bsum, int nb) {
  const int t = threadIdx.x;
  const int orig = (t < nb) ? bsum[t] : 0;
  int v = orig;
  for (int off = 1; off < 64; off <<= 1) {
    const int u = __shfl_up(v, off);
    if (t >= off) v += u;
  }
  if (t < nb) bsum[t] = v - orig;   // exclusive
}

__global__ __launch_bounds__(256) void scan_final(
    int* __restrict__ cursor, const int* __restrict__ bsum, int N) {
  __shared__ int woff[4];
  const int base = blockIdx.x * SCAN_CH + threadIdx.x * 4;
  int x[4]; int s = 0;
#pragma unroll
  for (int j = 0; j < 4; ++j) { const int i = base + j; x[j] = (i < N) ? cursor[i] : 0; s += x[j]; }
  int v = s;
  const int lane = threadIdx.x & 63, wid = threadIdx.x >> 6;
  for (int off = 1; off < 64; off <<= 1) {
    const int u = __shfl_up(v, off);
    if (lane >= off) v += u;
  }
  if (lane == 63) woff[wid] = v;
  __syncthreads();
  int waveoff = 0;
  for (int k = 0; k < 4; ++k) waveoff += (k < wid) ? woff[k] : 0;
  int ex = v - s + waveoff + bsum[blockIdx.x];
#pragma unroll
  for (int j = 0; j < 4; ++j) {
    const int i = base + j;
    if (i < N) { cursor[i] = ex; ex += x[j]; }
  }
}

__global__ __launch_bounds__(256) void scatter_kernel(
    const int* __restrict__ eidx, int* __restrict__ cursor,
    uint32_t* __restrict__ sorted, int E) {
  const int e = blockIdx.x * 256 + threadIdx.x;
  if (e < E) {
    const int s = eidx[e];
    const int d = eidx[E + e];
    const int slot = atomicAdd(&cursor[d], 1);
    sorted[slot] = ((uint32_t)d << 16) | (uint32_t)s;
  }
}

// ================= edge kernel =================
__global__ __launch_bounds__(512, 4) void edge_mfma_kernel(
    const float* __restrict__ pos,
    const unsigned short* __restrict__ vbf, const unsigned short* __restrict__ abf,
    const float* __restrict__ adst,
    const float* __restrict__ pW1, const float* __restrict__ pb1,
    const float* __restrict__ pb2, const float* __restrict__ ab1, const float* __restrict__ ab2,
    const uint4* __restrict__ frag,
    const uint32_t* __restrict__ sorted,
    float* __restrict__ num, float* __restrict__ den, int E) {
  __shared__ uint32_t sWfrag[24][64][4];
  __shared__ float    sSmall[448];
  __shared__ float    sXp[8][16 * 68];
  __shared__ int      sDst[8][16];

  const int tid = threadIdx.x;
  for (int i = tid; i < 448; i += 512) {
    float val;
    if      (i < 192) val = pW1[i];
    else if (i < 256) val = pb1[i - 192];
    else if (i < 320) val = pb2[i - 256];
    else if (i < 384) val = ab1[i - 320];
    else              val = ab2[i - 384];
    sSmall[i] = val;
  }
  {
    uint4* sW4 = (uint4*)sWfrag;
    for (int i = tid; i < 24 * 64; i += 512) sW4[i] = frag[i];
  }
  __syncthreads();

  const int w  = tid >> 6, l = tid & 63;
  const int lo = l & 15,  hi = l >> 4;
  float*   xb     = &sXp[w][0];
  uint8_t* trbase = (uint8_t*)xb;
  const uint32_t swz = (uint32_t)((lo & 7) << 4);
  const int ho = hi * 8;

#define WF(m, half, t) (*(const bf16x8*)&sWfrag[(m) * 8 + (half) * 4 + (t)][l][0])

  const int ntiles = (E + 15) >> 4;
  const int stride = gridDim.x * 8;

  int cs = 0, cd = 0; float c0 = 0.f, c1 = 0.f, c2 = 0.f;
  {
    const int t0 = blockIdx.x * 8 + w;
    if (t0 < ntiles) {
      const int ee = t0 * 16 + lo;
      const int ec = ee < E ? ee : (E - 1);
      const uint32_t se = sorted[ec];
      cs = (int)(se & 0xFFFFu); cd = (int)(se >> 16);
      c0 = pos[cd * 3 + 0] - pos[cs * 3 + 0];
      c1 = pos[cd * 3 + 1] - pos[cs * 3 + 1];
      c2 = pos[cd * 3 + 2] - pos[cs * 3 + 2];
    }
  }

  for (int tile = blockIdx.x * 8 + w; tile < ntiles; tile += stride) {
    const int src = cs, dst = cd;
    const float d0 = c0, d1 = c1, d2 = c2;
    const size_t db = (size_t)dst * 64, sb = (size_t)src * 64;

    const f32x4 Ad00 = *(const f32x4*)&adst[db + ho];
    const f32x4 Ad01 = *(const f32x4*)&adst[db + ho + 4];
    const f32x4 Ad10 = *(const f32x4*)&adst[db + 32 + ho];
    const f32x4 Ad11 = *(const f32x4*)&adst[db + 32 + ho + 4];
    const u16x8 As0  = *(const u16x8*)&abf[sb + ho];
    const u16x8 As1  = *(const u16x8*)&abf[sb + 32 + ho];

    const int nt = tile + stride;
    if (nt < ntiles) {
      const int ee = nt * 16 + lo;
      const int ec = ee < E ? ee : (E - 1);
      const uint32_t se = sorted[ec];
      cs = (int)(se & 0xFFFFu); cd = (int)(se >> 16);
      c0 = pos[cd * 3 + 0] - pos[cs * 3 + 0];
      c1 = pos[cd * 3 + 1] - pos[cs * 3 + 1];
      c2 = pos[cd * 3 + 2] - pos[cs * 3 + 2];
    }

    if (hi == 0) sDst[w][lo] = dst;

    // pos layer 1 (3->64)
    bf16x8 hf[2];
#pragma unroll
    for (int half = 0; half < 2; ++half) {
      float t8[8];
#pragma unroll
      for (int i = 0; i < 8; ++i) {
        const int k = 32 * half + hi * 8 + i;
        t8[i] = fmaxf(sSmall[192 + k] + d0 * sSmall[k] + d1 * sSmall[64 + k] + d2 * sSmall[128 + k], 0.f);
      }
      hf[half] = mk8(cvtpk(t8[0], t8[1]), cvtpk(t8[2], t8[3]),
                     cvtpk(t8[4], t8[5]), cvtpk(t8[6], t8[7]));
    }
    // pos layer 2
    f32x4 dl[4];
#pragma unroll
    for (int t = 0; t < 4; ++t) {
      f32x4 acc = *(const f32x4*)&sSmall[256 + t * 16 + hi * 4];
      acc = mfma16(WF(0, 0, t), hf[0], acc);
      acc = mfma16(WF(0, 1, t), hf[1], acc);
#pragma unroll
      for (int r = 0; r < 4; ++r) dl[t][r] = fmaxf(acc[r], 0.f);
    }
    // transpose delta
    LGKM0;
#pragma unroll
    for (int t = 0; t < 4; ++t) {
      uint2 p; p.x = cvtpk(dl[t][0], dl[t][1]); p.y = cvtpk(dl[t][2], dl[t][3]);
      *(uint2*)(trbase + lo * 128 + (((uint32_t)(t * 32 + hi * 8)) ^ swz)) = p;
    }
    LGKM0;
    const bf16x8 dfr0 = *(const bf16x8*)(trbase + lo * 128 + (((uint32_t)(hi * 16)) ^ swz));
    const bf16x8 dfr1 = *(const bf16x8*)(trbase + lo * 128 + (((uint32_t)(64 + hi * 16)) ^ swz));

    bf16x8 tf[2];
    {
      float t8[8];
#pragma unroll
      for (int i = 0; i < 8; ++i)
        t8[i] = ((i < 4) ? Ad00[i] : Ad01[i - 4]) - bf2f(As0[i]) + bf2fs(dfr0[i]);
      tf[0] = mk8(cvtpk(t8[0], t8[1]), cvtpk(t8[2], t8[3]),
                  cvtpk(t8[4], t8[5]), cvtpk(t8[6], t8[7]));
#pragma unroll
      for (int i = 0; i < 8; ++i)
        t8[i] = ((i < 4) ? Ad10[i] : Ad11[i - 4]) - bf2f(As1[i]) + bf2fs(dfr1[i]);
      tf[1] = mk8(cvtpk(t8[0], t8[1]), cvtpk(t8[2], t8[3]),
                  cvtpk(t8[4], t8[5]), cvtpk(t8[6], t8[7]));
    }

    u16x4 V[4];
#pragma unroll
    for (int t = 0; t < 4; ++t) V[t] = *(const u16x4*)&vbf[sb + t * 16 + hi * 4];

    // attn layer 1
    f32x4 ga[4];
#pragma unroll
    for (int t = 0; t < 4; ++t) {
      f32x4 acc = *(const f32x4*)&sSmall[320 + t * 16 + hi * 4];
      acc = mfma16(WF(1, 0, t), tf[0], acc);
      acc = mfma16(WF(1, 1, t), tf[1], acc);
#pragma unroll
      for (int r = 0; r < 4; ++r) ga[t][r] = fmaxf(acc[r], 0.f);
    }
#pragma unroll
    for (int t = 0; t < 4; ++t) {
      uint2 p; p.x = cvtpk(ga[t][0], ga[t][1]); p.y = cvtpk(ga[t][2], ga[t][3]);
      *(uint2*)(trbase + 2048 + lo * 128 + (((uint32_t)(t * 32 + hi * 8)) ^ swz)) = p;
    }
    LGKM0;
    const bf16x8 gf0 = *(const bf16x8*)(trbase + 2048 + lo * 128 + (((uint32_t)(hi * 16)) ^ swz));
    const bf16x8 gf1 = *(const bf16x8*)(trbase + 2048 + lo * 128 + (((uint32_t)(64 + hi * 16)) ^ swz));

    // attn layer 2 -> ex
    f32x4 exv[4];
#pragma unroll
    for (int t = 0; t < 4; ++t) {
      f32x4 acc = *(const f32x4*)&sSmall[384 + t * 16 + hi * 4];
      acc = mfma16(WF(2, 0, t), gf0, acc);
      acc = mfma16(WF(2, 1, t), gf1, acc);
      f32x4 nv;
#pragma unroll
      for (int r = 0; r < 4; ++r) {
        const float ex = __expf(fmaxf(acc[r], 0.f));
        exv[t][r] = ex;
        nv[r] = ex * (bf2f(V[t][r]) + dl[t][r]);
      }
      *(f32x4*)&xb[lo * 68 + t * 16 + hi * 4] = nv;
    }
    LGKM0;
    const int tbase = tile * 16;
    {
      int run_d = __builtin_amdgcn_readfirstlane(sDst[w][0]);
      float acc = 0.f;
#pragma unroll
      for (int ee = 0; ee < 16; ++ee) {
        if (tbase + ee < E) {
          const int de = __builtin_amdgcn_readfirstlane(sDst[w][ee]);
          const float nv = xb[ee * 68 + l];
          if (de != run_d) {
            atomicAdd(&num[(size_t)run_d * 64 + l], acc);
            run_d = de; acc = 0.f;
          }
          acc += nv;
        }
      }
      atomicAdd(&num[(size_t)run_d * 64 + l], acc);
    }
#pragma unroll
    for (int t = 0; t < 4; ++t)
      *(f32x4*)&xb[lo * 68 + t * 16 + hi * 4] = exv[t];
    LGKM0;
    {
      int run_d = __builtin_amdgcn_readfirstlane(sDst[w][0]);
      float acc = 0.f;
#pragma unroll
      for (int ee = 0; ee < 16; ++ee) {
        if (tbase + ee < E) {
          const int de = __builtin_amdgcn_readfirstlane(sDst[w][ee]);
          const float dv = xb[ee * 68 + l];
          if (de != run_d) {
            atomicAdd(&den[(size_t)run_d * 64 + l], acc);
            run_d = de; acc = 0.f;
          }
          acc += dv;
        }
      }
      atomicAdd(&den[(size_t)run_d * 64 + l], acc);
    }
  }
#undef WF
}

// ================= node_out (MFMA) =================
__global__ __launch_bounds__(512, 4) void node_out_mfma(
    const float* __restrict__ num, const float* __restrict__ den,
    const uint4* __restrict__ frag, const float* __restrict__ b_out,
    float* __restrict__ out, int N) {
  __shared__ uint32_t sWfrag[8][64][4];
  __shared__ float    sBias[64];
  __shared__ float    sXp[8][16 * 68];

  const int tid = threadIdx.x;
  {
    uint4* sW4 = (uint4*)sWfrag;
    const uint4* src = frag + 56 * 64;
    for (int i = tid; i < 8 * 64; i += 512) sW4[i] = src[i];
  }
  if (tid < 64) sBias[tid] = b_out[tid];
  __syncthreads();

  const int w  = tid >> 6, l = tid & 63;
  const int lo = l & 15,  hi = l >> 4;
  float* xb = &sXp[w][0];

#define WFo(half, t) (*(const bf16x8*)&sWfrag[(half) * 4 + (t)][l][0])

  const int ntiles = (N + 15) >> 4;
  for (int tile = blockIdx.x * 8 + w; tile < ntiles; tile += gridDim.x * 8) {
    const int row = tile * 16 + lo;
    const int rowc = row < N ? row : (N - 1);
    bf16x8 sf[2];
#pragma unroll
    for (int half = 0; half < 2; ++half) {
      const int base = 32 * half + hi * 8;
      const f32x4 N0 = *(const f32x4*)&num[(size_t)rowc * 64 + base];
      const f32x4 N1 = *(const f32x4*)&num[(size_t)rowc * 64 + base + 4];
      const f32x4 D0 = *(const f32x4*)&den[(size_t)rowc * 64 + base];
      const f32x4 D1 = *(const f32x4*)&den[(size_t)rowc * 64 + base + 4];
      float t8[8];
#pragma unroll
      for (int i = 0; i < 8; ++i) {
        const float nn = (i < 4) ? N0[i] : N1[i - 4];
        const float dd = (i < 4) ? D0[i] : D1[i - 4];
        t8[i] = nn / (dd + 1e-16f);
      }
      sf[half] = mk8(cvtpk(t8[0], t8[1]), cvtpk(t8[2], t8[3]),
                     cvtpk(t8[4], t8[5]), cvtpk(t8[6], t8[7]));
    }
    f32x4 res[4];
#pragma unroll
    for (int t = 0; t < 4; ++t) {
      f32x4 acc = *(const f32x4*)&sBias[t * 16 + hi * 4];
      acc = mfma16(WFo(0, t), sf[0], acc);
      acc = mfma16(WFo(1, t), sf[1], acc);
#pragma unroll
      for (int r = 0; r < 4; ++r) res[t][r] = fmaxf(acc[r], 0.f);
    }
    LGKM0;
#pragma unroll
    for (int t = 0; t < 4; ++t)
      *(f32x4*)&xb[lo * 68 + t * 16 + hi * 4] = res[t];
    LGKM0;
#pragma unroll
    for (int ee = 0; ee < 16; ++ee) {
      const int r2 = tile * 16 + ee;
      if (r2 < N) out[(size_t)r2 * 64 + l] = xb[ee * 68 + l];
    }
  }
#undef WFo
}

extern "C" void kernel_launch(void* const* d_in, const int* in_sizes, int n_in,
                              void* d_out, int out_size, void* d_ws, size_t ws_size,
                              hipStream_t stream) {
  const float* x     = (const float*)d_in[0];
  const float* pos   = (const float*)d_in[1];
  const float* W_in  = (const float*)d_in[2];
  const float* b_in  = (const float*)d_in[3];
  const float* W_lin = (const float*)d_in[4];
  const float* W_src = (const float*)d_in[5];
  const float* W_dst = (const float*)d_in[6];
  const float* pW1   = (const float*)d_in[7];
  const float* pb1   = (const float*)d_in[8];
  const float* pW2   = (const float*)d_in[9];
  const float* pb2   = (const float*)d_in[10];
  const float* aW1   = (const float*)d_in[11];
  const float* ab1   = (const float*)d_in[12];
  const float* aW2   = (const float*)d_in[13];
  const float* ab2   = (const float*)d_in[14];
  const float* W_out = (const float*)d_in[15];
  const float* b_out = (const float*)d_in[16];
  const int*   eidx  = (const int*)d_in[17];

  const int N = in_sizes[0] / 64;
  const int E = in_sizes[17] / 2;

  // workspace layout (memset region first, contiguous)
  char* p = (char*)d_ws;
  float* num    = (float*)p;  p += (size_t)N * 64 * 4;
  float* den    = (float*)p;  p += (size_t)N * 64 * 4;
  int*   cursor = (int*)p;    p += (size_t)N * 4;
  const size_t memset_bytes = (size_t)p - (size_t)d_ws;
  int*   bsum   = (int*)p;    p += 64 * 4;
  p = (char*)(((uintptr_t)p + 15) & ~(uintptr_t)15);
  uint4* frag   = (uint4*)p;  p += (size_t)4096 * 16;
  uint32_t* sorted = (uint32_t*)p; p += (size_t)E * 4;
  unsigned short* vbf = (unsigned short*)p; p += (size_t)N * 64 * 2;
  unsigned short* abf = (unsigned short*)p; p += (size_t)N * 64 * 2;
  float* adst   = (float*)p;  p += (size_t)N * 64 * 4;

  hipMemsetAsync(d_ws, 0, memset_bytes, stream);

  const int HB = (E + 1023) / 1024;      // hist blocks (4 edges/thread)
  const int NB_NODE = 784;
  fused_prep_kernel<<<16 + HB + NB_NODE, 256, 0, stream>>>(
      pW2, aW1, aW2, W_in, W_lin, W_src, W_dst, W_out, frag,
      eidx, cursor, E,
      x, b_in, vbf, abf, adst, N, HB);

  const int nb = (N + SCAN_CH - 1) / SCAN_CH;
  scan_blocksum<<<nb, 256, 0, stream>>>(cursor, bsum, N);
  scan_bsum_prefix<<<1, 64, 0, stream>>>(bsum, nb);
  scan_final<<<nb, 256, 0, stream>>>(cursor, bsum, N);
  scatter_kernel<<<(E + 255) / 256, 256, 0, stream>>>(eidx, cursor, sorted, E);

  edge_mfma_kernel<<<512, 512, 0, stream>>>(pos, vbf, abf, adst,
                                            pW1, pb1, pb2, ab1, ab2,
                                            frag, sorted, num, den, E);
  node_out_mfma<<<392, 512, 0, stream>>>(num, den, frag, b_out, (float*)d_out, N);
}